// Round 1
// baseline (9967.615 us; speedup 1.0000x reference)
//
#include <hip/hip_runtime.h>
#include <math.h>

#define NN 50000
#define IN_DIM 16
#define DD 128
#define HH 256
#define NE 800000
#define NLAYERS 3
#define ET (NE + NN)

__device__ __forceinline__ float fast_tanh(float x) {
  float ax = fabsf(x);
  float e = __expf(2.0f * ax);
  float t = 1.0f - __fdividef(2.0f, e + 1.0f);
  return copysignf(t, x);
}

__device__ __forceinline__ float fast_sigmoid(float x) {
  return __fdividef(1.0f, 1.0f + __expf(-x));
}

__global__ void counts_init_kernel(float* counts) {
  int n = blockIdx.x * blockDim.x + threadIdx.x;
  if (n < NN) counts[n] = 1.0f;  // self loop
}

__global__ void counts_accum_kernel(const int* __restrict__ tgt, float* counts) {
  int e = blockIdx.x * blockDim.x + threadIdx.x;
  if (e < NE) atomicAdd(&counts[tgt[e]], 1.0f);
}

__global__ void counts_inv_kernel(float* counts) {
  int n = blockIdx.x * blockDim.x + threadIdx.x;
  if (n < NN) counts[n] = 1.0f / counts[n];
}

__global__ void encoder_kernel(const float* __restrict__ x, const float* __restrict__ W,
                               const float* __restrict__ b, float* __restrict__ h) {
  int idx = blockIdx.x * blockDim.x + threadIdx.x;
  if (idx >= NN * DD) return;
  int n = idx >> 7, j = idx & (DD - 1);
  const float* xr = x + n * IN_DIM;
  float acc = b[j];
#pragma unroll
  for (int k = 0; k < IN_DIM; ++k) acc = fmaf(xr[k], W[k * DD + j], acc);
  h[idx] = fast_tanh(acc);
}

// C[M x NO] = act(A[M x K] @ B[K x NO] + bias). Block: 64 rows x 128 cols.
template <int K, bool TANH>
__global__ __launch_bounds__(256) void gemm_kernel(
    const float* __restrict__ A, const float* __restrict__ B,
    const float* __restrict__ bias, float* __restrict__ C, int M, int NO) {
  constexpr int KP = K + 4;
  __shared__ float As[64 * KP];
  const int t = threadIdx.x;
  const int row0 = blockIdx.x * 64;
  const int j0 = blockIdx.y * 128;
  {
    const int nf4 = K / 4;
    for (int i = t; i < 64 * nf4; i += 256) {
      int r = i / nf4;
      int kc = (i - r * nf4) * 4;
      int row = row0 + r;
      float4 v4 = make_float4(0.f, 0.f, 0.f, 0.f);
      if (row < M) v4 = *(const float4*)(A + (size_t)row * K + kc);
      *(float4*)&As[r * KP + kc] = v4;
    }
  }
  __syncthreads();
  const int te = t >> 5;
  const int tj = t & 31;
  const int jj = j0 + tj * 4;
  float acc[8][4];
#pragma unroll
  for (int i = 0; i < 8; ++i)
#pragma unroll
    for (int j = 0; j < 4; ++j) acc[i][j] = 0.f;
  const float* Bp = B + jj;
  const float* as0 = As + te * 8 * KP;
  for (int k = 0; k < K; k += 4) {
    float wv[4][4];
#pragma unroll
    for (int kk = 0; kk < 4; ++kk) {
      float4 w4 = *(const float4*)(Bp + (size_t)(k + kk) * NO);
      wv[kk][0] = w4.x; wv[kk][1] = w4.y; wv[kk][2] = w4.z; wv[kk][3] = w4.w;
    }
#pragma unroll
    for (int i = 0; i < 8; ++i) {
      float4 a4 = *(const float4*)(as0 + i * KP + k);
      float va[4] = {a4.x, a4.y, a4.z, a4.w};
#pragma unroll
      for (int j = 0; j < 4; ++j) {
        acc[i][j] = fmaf(va[0], wv[0][j], acc[i][j]);
        acc[i][j] = fmaf(va[1], wv[1][j], acc[i][j]);
        acc[i][j] = fmaf(va[2], wv[2][j], acc[i][j]);
        acc[i][j] = fmaf(va[3], wv[3][j], acc[i][j]);
      }
    }
  }
  float bb[4] = {0.f, 0.f, 0.f, 0.f};
  if (bias) {
    float4 b4 = *(const float4*)(bias + jj);
    bb[0] = b4.x; bb[1] = b4.y; bb[2] = b4.z; bb[3] = b4.w;
  }
#pragma unroll
  for (int i = 0; i < 8; ++i) {
    int row = row0 + te * 8 + i;
    if (row < M) {
      float v0 = acc[i][0] + bb[0], v1 = acc[i][1] + bb[1];
      float v2 = acc[i][2] + bb[2], v3 = acc[i][3] + bb[3];
      if (TANH) {
        v0 = fast_tanh(v0); v1 = fast_tanh(v1);
        v2 = fast_tanh(v2); v3 = fast_tanh(v3);
      }
      float4 o; o.x = v0; o.y = v1; o.z = v2; o.w = v3;
      *(float4*)(C + (size_t)row * NO + jj) = o;
    }
  }
}

// Per-edge MLP: v = tanh(Pt[tgt]+Ps[src]); u = tanh(v@W2+b2); w = u@W3+b3;
// atomicAdd into agg[tgt]. 64 edges per block, 256 threads.
__global__ __launch_bounds__(256) void edge_kernel(
    const int* __restrict__ esrc, const int* __restrict__ etgt,
    const float* __restrict__ Pt, const float* __restrict__ Ps,
    const float* __restrict__ W2, const float* __restrict__ b2,
    const float* __restrict__ W3, const float* __restrict__ b3,
    float* __restrict__ agg) {
  constexpr int VP = HH + 4;  // 260, pad to break bank conflicts
  __shared__ float v[64 * VP];
  __shared__ int sIdx[64];
  __shared__ int tIdx[64];
  const int t = threadIdx.x;
  const int e0 = blockIdx.x * 64;
  if (t < 64) {
    int e = e0 + t;
    int s = 0, tg = -1;
    if (e < NE) { s = esrc[e]; tg = etgt[e]; }
    else if (e < ET) { s = e - NE; tg = s; }
    sIdx[t] = s;
    tIdx[t] = tg;
  }
  __syncthreads();
  // stage 1: gather + tanh -> v in LDS (4 threads per edge)
  {
    const int el = t >> 2;
    const int kc0 = (t & 3) * 64;
    int tg = tIdx[el]; if (tg < 0) tg = 0;
    const int s = sIdx[el];
    const float4* pt = (const float4*)(Pt + (size_t)tg * HH + kc0);
    const float4* ps = (const float4*)(Ps + (size_t)s * HH + kc0);
    float* vrow = v + el * VP + kc0;
#pragma unroll
    for (int i = 0; i < 16; ++i) {
      float4 a = pt[i];
      float4 b = ps[i];
      float4 o;
      o.x = fast_tanh(a.x + b.x);
      o.y = fast_tanh(a.y + b.y);
      o.z = fast_tanh(a.z + b.z);
      o.w = fast_tanh(a.w + b.w);
      *(float4*)(vrow + i * 4) = o;
    }
  }
  __syncthreads();
  const int te = t >> 5;
  const int tj = t & 31;
  // stage 2: u = tanh(v @ W2 + b2), thread tile 8 edges x 8 cols
  float acc[8][8];
  {
    const int j0 = tj * 8;
#pragma unroll
    for (int j = 0; j < 8; ++j) {
      float bj = b2[j0 + j];
#pragma unroll
      for (int i = 0; i < 8; ++i) acc[i][j] = bj;
    }
    const float* W2p = W2 + j0;
    const float* vs0 = v + te * 8 * VP;
    for (int k = 0; k < HH; k += 4) {
      float wv[4][8];
#pragma unroll
      for (int kk = 0; kk < 4; ++kk) {
        float4 w0 = *(const float4*)(W2p + (size_t)(k + kk) * HH);
        float4 w1 = *(const float4*)(W2p + (size_t)(k + kk) * HH + 4);
        wv[kk][0] = w0.x; wv[kk][1] = w0.y; wv[kk][2] = w0.z; wv[kk][3] = w0.w;
        wv[kk][4] = w1.x; wv[kk][5] = w1.y; wv[kk][6] = w1.z; wv[kk][7] = w1.w;
      }
#pragma unroll
      for (int i = 0; i < 8; ++i) {
        float4 a4 = *(const float4*)(vs0 + i * VP + k);
        float va[4] = {a4.x, a4.y, a4.z, a4.w};
#pragma unroll
        for (int j = 0; j < 8; ++j) {
          acc[i][j] = fmaf(va[0], wv[0][j], acc[i][j]);
          acc[i][j] = fmaf(va[1], wv[1][j], acc[i][j]);
          acc[i][j] = fmaf(va[2], wv[2][j], acc[i][j]);
          acc[i][j] = fmaf(va[3], wv[3][j], acc[i][j]);
        }
      }
    }
  }
  __syncthreads();  // all reads of v done
  {
    const int j0 = tj * 8;
#pragma unroll
    for (int i = 0; i < 8; ++i) {
      float* ur = v + (te * 8 + i) * VP + j0;
      float4 o0, o1;
      o0.x = fast_tanh(acc[i][0]); o0.y = fast_tanh(acc[i][1]);
      o0.z = fast_tanh(acc[i][2]); o0.w = fast_tanh(acc[i][3]);
      o1.x = fast_tanh(acc[i][4]); o1.y = fast_tanh(acc[i][5]);
      o1.z = fast_tanh(acc[i][6]); o1.w = fast_tanh(acc[i][7]);
      *(float4*)ur = o0;
      *(float4*)(ur + 4) = o1;
    }
  }
  __syncthreads();
  // stage 3: w = u @ W3 + b3 ; scatter-add. thread tile 8 edges x 4 cols
  {
    const int j2 = tj * 4;
    float acc2[8][4];
    float4 b4 = *(const float4*)(b3 + j2);
#pragma unroll
    for (int i = 0; i < 8; ++i) {
      acc2[i][0] = b4.x; acc2[i][1] = b4.y; acc2[i][2] = b4.z; acc2[i][3] = b4.w;
    }
    const float* W3p = W3 + j2;
    const float* vs0 = v + te * 8 * VP;
    for (int k = 0; k < HH; k += 4) {
      float wv[4][4];
#pragma unroll
      for (int kk = 0; kk < 4; ++kk) {
        float4 w4 = *(const float4*)(W3p + (size_t)(k + kk) * DD);
        wv[kk][0] = w4.x; wv[kk][1] = w4.y; wv[kk][2] = w4.z; wv[kk][3] = w4.w;
      }
#pragma unroll
      for (int i = 0; i < 8; ++i) {
        float4 a4 = *(const float4*)(vs0 + i * VP + k);
        float va[4] = {a4.x, a4.y, a4.z, a4.w};
#pragma unroll
        for (int j = 0; j < 4; ++j) {
          acc2[i][j] = fmaf(va[0], wv[0][j], acc2[i][j]);
          acc2[i][j] = fmaf(va[1], wv[1][j], acc2[i][j]);
          acc2[i][j] = fmaf(va[2], wv[2][j], acc2[i][j]);
          acc2[i][j] = fmaf(va[3], wv[3][j], acc2[i][j]);
        }
      }
    }
#pragma unroll
    for (int i = 0; i < 8; ++i) {
      int tg = tIdx[te * 8 + i];
      if (tg >= 0) {
        float* ap = agg + (size_t)tg * DD + j2;
        atomicAdd(ap + 0, acc2[i][0]);
        atomicAdd(ap + 1, acc2[i][1]);
        atomicAdd(ap + 2, acc2[i][2]);
        atomicAdd(ap + 3, acc2[i][3]);
      }
    }
  }
}

__global__ void scale_agg_kernel(float* agg, const float* __restrict__ inv_counts) {
  int idx = blockIdx.x * blockDim.x + threadIdx.x;
  if (idx >= NN * DD) return;
  agg[idx] *= inv_counts[idx >> 7];
}

__global__ void gru_gate_kernel(const float* __restrict__ gi, const float* __restrict__ gh,
                                float* __restrict__ h) {
  int idx = blockIdx.x * blockDim.x + threadIdx.x;
  if (idx >= NN * DD) return;
  int n = idx >> 7, j = idx & (DD - 1);
  const float* gir = gi + (size_t)n * (3 * DD);
  const float* ghr = gh + (size_t)n * (3 * DD);
  float r = fast_sigmoid(gir[j] + ghr[j]);
  float z = fast_sigmoid(gir[DD + j] + ghr[DD + j]);
  float nv = fast_tanh(gir[2 * DD + j] + r * ghr[2 * DD + j]);
  float hv = h[idx];
  h[idx] = (1.0f - z) * nv + z * hv;
}

__global__ __launch_bounds__(256) void dec3_kernel(const float* __restrict__ o2,
                                                   const float* __restrict__ W3,
                                                   const float* __restrict__ b3,
                                                   float* __restrict__ out) {
  int lane = threadIdx.x & 63;
  int n = blockIdx.x * 4 + (threadIdx.x >> 6);
  if (n >= NN) return;
  const float* r = o2 + (size_t)n * HH;
  float p = 0.f;
#pragma unroll
  for (int i = 0; i < 4; ++i) p = fmaf(r[lane + 64 * i], W3[lane + 64 * i], p);
  for (int off = 32; off > 0; off >>= 1) p += __shfl_down(p, off);
  if (lane == 0) out[n] = p + b3[0];
}

extern "C" void kernel_launch(void* const* d_in, const int* in_sizes, int n_in,
                              void* d_out, int out_size, void* d_ws, size_t ws_size,
                              hipStream_t stream) {
  const float* x      = (const float*)d_in[0];
  const int*   ei     = (const int*)d_in[1];
  const float* enc_W  = (const float*)d_in[2];
  const float* enc_b  = (const float*)d_in[3];
  const float* msg_W1 = (const float*)d_in[4];
  const float* msg_b1 = (const float*)d_in[5];
  const float* msg_W2 = (const float*)d_in[6];
  const float* msg_b2 = (const float*)d_in[7];
  const float* msg_W3 = (const float*)d_in[8];
  const float* msg_b3 = (const float*)d_in[9];
  const float* gWih   = (const float*)d_in[10];
  const float* gWhh   = (const float*)d_in[11];
  const float* gbih   = (const float*)d_in[12];
  const float* gbhh   = (const float*)d_in[13];
  const float* dW1    = (const float*)d_in[14];
  const float* db1    = (const float*)d_in[15];
  const float* dW2    = (const float*)d_in[16];
  const float* db2    = (const float*)d_in[17];
  const float* dW3    = (const float*)d_in[18];
  const float* db3    = (const float*)d_in[19];
  float* out = (float*)d_out;

  float* ws = (float*)d_ws;
  float* counts = ws;                                 // N
  float* h      = ws + NN;                            // 128N
  float* agg    = h + (size_t)NN * DD;                // 128N
  float* R      = agg + (size_t)NN * DD;              // 768N shared scratch
  float* Pt = R;
  float* Ps = R + (size_t)NN * HH;
  float* gi = R;                                      // alias (P dead by then)
  float* gh = R + (size_t)NN * 3 * DD;
  float* o1 = R;                                      // alias (gi dead by then)
  float* o2 = R + (size_t)NN * HH;

  const int* esrc = ei;        // edge_index[0] = x_j source
  const int* etgt = ei + NE;   // edge_index[1] = aggregation bucket

  counts_init_kernel<<<(NN + 255) / 256, 256, 0, stream>>>(counts);
  counts_accum_kernel<<<(NE + 255) / 256, 256, 0, stream>>>(etgt, counts);
  counts_inv_kernel<<<(NN + 255) / 256, 256, 0, stream>>>(counts);
  encoder_kernel<<<(NN * DD + 255) / 256, 256, 0, stream>>>(x, enc_W, enc_b, h);

  dim3 gP((NN + 63) / 64, 2);   // NO=256
  dim3 gG((NN + 63) / 64, 3);   // NO=384
  for (int l = 0; l < NLAYERS; ++l) {
    const float* W1 = msg_W1 + (size_t)l * 2 * DD * HH;
    gemm_kernel<DD, false><<<gP, 256, 0, stream>>>(h, W1, msg_b1 + l * HH, Pt, NN, HH);
    gemm_kernel<DD, false><<<gP, 256, 0, stream>>>(h, W1 + (size_t)DD * HH, nullptr, Ps, NN, HH);
    hipMemsetAsync(agg, 0, (size_t)NN * DD * sizeof(float), stream);
    edge_kernel<<<(ET + 63) / 64, 256, 0, stream>>>(
        esrc, etgt, Pt, Ps,
        msg_W2 + (size_t)l * HH * HH, msg_b2 + (size_t)l * HH,
        msg_W3 + (size_t)l * HH * DD, msg_b3 + (size_t)l * DD, agg);
    scale_agg_kernel<<<(NN * DD + 255) / 256, 256, 0, stream>>>(agg, counts);
    gemm_kernel<DD, false><<<gG, 256, 0, stream>>>(
        agg, gWih + (size_t)l * DD * 3 * DD, gbih + (size_t)l * 3 * DD, gi, NN, 3 * DD);
    gemm_kernel<DD, false><<<gG, 256, 0, stream>>>(
        h, gWhh + (size_t)l * DD * 3 * DD, gbhh + (size_t)l * 3 * DD, gh, NN, 3 * DD);
    gru_gate_kernel<<<(NN * DD + 255) / 256, 256, 0, stream>>>(gi, gh, h);
  }
  gemm_kernel<DD, true><<<gP, 256, 0, stream>>>(h, dW1, db1, o1, NN, HH);
  gemm_kernel<HH, true><<<gP, 256, 0, stream>>>(o1, dW2, db2, o2, NN, HH);
  dec3_kernel<<<NN / 4, 256, 0, stream>>>(o2, dW3, db3, out);
}

// Round 2
// 7032.251 us; speedup vs baseline: 1.4174x; 1.4174x over previous
//
#include <hip/hip_runtime.h>
#include <math.h>

#define NN 50000
#define IN_DIM 16
#define DD 128
#define HH 256
#define NE 800000
#define NLAYERS 3
#define ET (NE + NN)

typedef unsigned short ushort_t;
typedef unsigned int uint_t;
typedef __attribute__((ext_vector_type(8))) short bf16x8;   // 8 bf16 = 4 VGPRs
typedef __attribute__((ext_vector_type(4))) float f32x4;

__device__ __forceinline__ float fast_tanh(float x) {
  float ax = fabsf(x);
  float e = __expf(2.0f * ax);
  float t = 1.0f - __fdividef(2.0f, e + 1.0f);
  return copysignf(t, x);
}

// branch-free tanh for the edge path: 1 - 2/(e^{2x}+1); inf/0 endpoints are exact
__device__ __forceinline__ float tanh_u(float x) {
  float e = __expf(2.0f * x);
  return 1.0f - __fdividef(2.0f, e + 1.0f);
}

__device__ __forceinline__ float fast_sigmoid(float x) {
  return __fdividef(1.0f, 1.0f + __expf(-x));
}

__device__ __forceinline__ ushort_t f2bf(float f) {  // RNE fp32->bf16
  uint_t u = __float_as_uint(f);
  u += 0x7FFFu + ((u >> 16) & 1u);
  return (ushort_t)(u >> 16);
}

__global__ void counts_init_kernel(float* counts) {
  int n = blockIdx.x * blockDim.x + threadIdx.x;
  if (n < NN) counts[n] = 1.0f;  // self loop
}

__global__ void counts_accum_kernel(const int* __restrict__ tgt, float* counts) {
  int e = blockIdx.x * blockDim.x + threadIdx.x;
  if (e < NE) atomicAdd(&counts[tgt[e]], 1.0f);
}

__global__ void counts_inv_kernel(float* counts) {
  int n = blockIdx.x * blockDim.x + threadIdx.x;
  if (n < NN) counts[n] = 1.0f / counts[n];
}

__global__ void encoder_kernel(const float* __restrict__ x, const float* __restrict__ W,
                               const float* __restrict__ b, float* __restrict__ h) {
  int idx = blockIdx.x * blockDim.x + threadIdx.x;
  if (idx >= NN * DD) return;
  int n = idx >> 7, j = idx & (DD - 1);
  const float* xr = x + n * IN_DIM;
  float acc = b[j];
#pragma unroll
  for (int k = 0; k < IN_DIM; ++k) acc = fmaf(xr[k], W[k * DD + j], acc);
  h[idx] = fast_tanh(acc);
}

// Pack W[K x M] (row-major, K multiple of 32, M multiple of 16) into bf16
// A-fragment order for u^T = W^T @ v^T:
//   out[((rt*8+ks)*64 + lane)*8 + j] = bf16(W[(ks*32 + (lane>>4)*8 + j)*M + rt*16 + (lane&15)])
__global__ void pack_weight_kernel(const float* __restrict__ W, ushort_t* __restrict__ out,
                                   int M, int ngrp) {
  int tid = blockIdx.x * blockDim.x + threadIdx.x;
  if (tid >= ngrp * 64) return;
  int lane = tid & 63;
  int g = tid >> 6;
  int rt = g >> 3, ks = g & 7;
  int m = rt * 16 + (lane & 15);
  int k0 = ks * 32 + ((lane >> 4) << 3);
  uint4 o;
  uint_t p[4];
#pragma unroll
  for (int d = 0; d < 4; ++d) {
    ushort_t lo = f2bf(W[(size_t)(k0 + 2 * d) * M + m]);
    ushort_t hi = f2bf(W[(size_t)(k0 + 2 * d + 1) * M + m]);
    p[d] = (uint_t)lo | ((uint_t)hi << 16);
  }
  o.x = p[0]; o.y = p[1]; o.z = p[2]; o.w = p[3];
  *(uint4*)(out + (size_t)tid * 8) = o;
}

// C[M x NO] = act(A[M x K] @ B[K x NO] + bias). Block: 64 rows x 128 cols. (fp32 node GEMM)
template <int K, bool TANH>
__global__ __launch_bounds__(256) void gemm_kernel(
    const float* __restrict__ A, const float* __restrict__ B,
    const float* __restrict__ bias, float* __restrict__ C, int M, int NO) {
  constexpr int KP = K + 4;
  __shared__ float As[64 * KP];
  const int t = threadIdx.x;
  const int row0 = blockIdx.x * 64;
  const int j0 = blockIdx.y * 128;
  {
    const int nf4 = K / 4;
    for (int i = t; i < 64 * nf4; i += 256) {
      int r = i / nf4;
      int kc = (i - r * nf4) * 4;
      int row = row0 + r;
      float4 v4 = make_float4(0.f, 0.f, 0.f, 0.f);
      if (row < M) v4 = *(const float4*)(A + (size_t)row * K + kc);
      *(float4*)&As[r * KP + kc] = v4;
    }
  }
  __syncthreads();
  const int te = t >> 5;
  const int tj = t & 31;
  const int jj = j0 + tj * 4;
  float acc[8][4];
#pragma unroll
  for (int i = 0; i < 8; ++i)
#pragma unroll
    for (int j = 0; j < 4; ++j) acc[i][j] = 0.f;
  const float* Bp = B + jj;
  const float* as0 = As + te * 8 * KP;
  for (int k = 0; k < K; k += 4) {
    float wv[4][4];
#pragma unroll
    for (int kk = 0; kk < 4; ++kk) {
      float4 w4 = *(const float4*)(Bp + (size_t)(k + kk) * NO);
      wv[kk][0] = w4.x; wv[kk][1] = w4.y; wv[kk][2] = w4.z; wv[kk][3] = w4.w;
    }
#pragma unroll
    for (int i = 0; i < 8; ++i) {
      float4 a4 = *(const float4*)(as0 + i * KP + k);
      float va[4] = {a4.x, a4.y, a4.z, a4.w};
#pragma unroll
      for (int j = 0; j < 4; ++j) {
        acc[i][j] = fmaf(va[0], wv[0][j], acc[i][j]);
        acc[i][j] = fmaf(va[1], wv[1][j], acc[i][j]);
        acc[i][j] = fmaf(va[2], wv[2][j], acc[i][j]);
        acc[i][j] = fmaf(va[3], wv[3][j], acc[i][j]);
      }
    }
  }
  float bb[4] = {0.f, 0.f, 0.f, 0.f};
  if (bias) {
    float4 b4 = *(const float4*)(bias + jj);
    bb[0] = b4.x; bb[1] = b4.y; bb[2] = b4.z; bb[3] = b4.w;
  }
#pragma unroll
  for (int i = 0; i < 8; ++i) {
    int row = row0 + te * 8 + i;
    if (row < M) {
      float v0 = acc[i][0] + bb[0], v1 = acc[i][1] + bb[1];
      float v2 = acc[i][2] + bb[2], v3 = acc[i][3] + bb[3];
      if (TANH) {
        v0 = fast_tanh(v0); v1 = fast_tanh(v1);
        v2 = fast_tanh(v2); v3 = fast_tanh(v3);
      }
      float4 o; o.x = v0; o.y = v1; o.z = v2; o.w = v3;
      *(float4*)(C + (size_t)row * NO + jj) = o;
    }
  }
}

// MFMA edge kernel. 64 edges/block, 256 threads (4 waves), wave w owns edges
// [w*16, w*16+16). Computes transposed so activations are B-operands:
//   u^T = tanh(W2^T @ v^T + b2),  msg^T = W3^T @ u^T + b3
// vB layout (bf16, LDS): granule[(ct*8+ks)*64 + quad*16 + mr][j] =
//   act[edge ct*16+mr][k = ks*32 + quad*8 + j]  (B-fragment order)
__global__ __launch_bounds__(256, 2) void edge_kernel(
    const int* __restrict__ esrc, const int* __restrict__ etgt,
    const float* __restrict__ Pt, const float* __restrict__ Ps,
    const ushort_t* __restrict__ W2p, const float* __restrict__ b2,
    const ushort_t* __restrict__ W3p, const float* __restrict__ b3,
    float* __restrict__ agg) {
  __shared__ ushort_t vB[4 * 8 * 64 * 8];  // 32 KiB
  __shared__ int sIdx[64];
  __shared__ int tIdx[64];
  const int t = threadIdx.x;
  const int e0 = blockIdx.x * 64;
  if (t < 64) {
    int e = e0 + t;
    int s = 0, tg = -1;
    if (e < NE) { s = esrc[e]; tg = etgt[e]; }
    else if (e < ET) { s = e - NE; tg = s; }
    sIdx[t] = s;
    tIdx[t] = tg;
  }
  __syncthreads();
  // stage 1: gather + tanh + bf16 -> vB. thread (el = t&63, c = t>>6) does k in [c*64, c*64+64)
  {
    const int el = t & 63, c = t >> 6;
    int tg = tIdx[el]; if (tg < 0) tg = 0;
    const int s = sIdx[el];
    const float4* pt = (const float4*)(Pt + (size_t)tg * HH + c * 64);
    const float4* ps = (const float4*)(Ps + (size_t)s * HH + c * 64);
    const int ct = el >> 4, mr = el & 15;
#pragma unroll
    for (int g = 0; g < 8; ++g) {
      float4 a0 = pt[2 * g], a1 = pt[2 * g + 1];
      float4 b0 = ps[2 * g], b1 = ps[2 * g + 1];
      float f[8] = {a0.x + b0.x, a0.y + b0.y, a0.z + b0.z, a0.w + b0.w,
                    a1.x + b1.x, a1.y + b1.y, a1.z + b1.z, a1.w + b1.w};
      uint4 o;
      uint_t p[4];
#pragma unroll
      for (int d = 0; d < 4; ++d) {
        ushort_t lo = f2bf(tanh_u(f[2 * d]));
        ushort_t hi = f2bf(tanh_u(f[2 * d + 1]));
        p[d] = (uint_t)lo | ((uint_t)hi << 16);
      }
      o.x = p[0]; o.y = p[1]; o.z = p[2]; o.w = p[3];
      const int ks = c * 2 + (g >> 2);
      const int quad = g & 3;
      *(uint4*)&vB[((ct * 8 + ks) * 64 + quad * 16 + mr) * 8] = o;
    }
  }
  __syncthreads();
  const int w = t >> 6, l = t & 63;
  const int quad = l >> 4, col = l & 15;
  // stage 2: u^T tiles. wave-private from here on (no more __syncthreads needed).
  f32x4 acc[16];
#pragma unroll
  for (int rt = 0; rt < 16; ++rt) acc[rt] = (f32x4){0.f, 0.f, 0.f, 0.f};
#pragma unroll
  for (int ks = 0; ks < 8; ++ks) {
    bf16x8 bfrag = *(const bf16x8*)&vB[((w * 8 + ks) * 64 + l) * 8];
#pragma unroll
    for (int rt = 0; rt < 16; ++rt) {
      bf16x8 afrag = *(const bf16x8*)&W2p[((size_t)(rt * 8 + ks) * 64 + l) * 8];
      acc[rt] = __builtin_amdgcn_mfma_f32_16x16x32_bf16(afrag, bfrag, acc[rt], 0, 0, 0);
    }
  }
  // bias + tanh + write u back into vB (B-fragment order), wave-private region
#pragma unroll
  for (int rt = 0; rt < 16; ++rt) {
    float4 bb = *(const float4*)(b2 + rt * 16 + quad * 4);
    float u0 = tanh_u(acc[rt][0] + bb.x);
    float u1 = tanh_u(acc[rt][1] + bb.y);
    float u2 = tanh_u(acc[rt][2] + bb.z);
    float u3 = tanh_u(acc[rt][3] + bb.w);
    uint2 d;
    d.x = (uint_t)f2bf(u0) | ((uint_t)f2bf(u1) << 16);
    d.y = (uint_t)f2bf(u2) | ((uint_t)f2bf(u3) << 16);
    // value u[edge=w*16+col][o], o = rt*16 + quad*4 + reg
    const int ks2 = rt >> 1;
    const int laned = ((rt & 1) * 2 + (quad >> 1)) * 16 + col;
    *(uint2*)&vB[((w * 8 + ks2) * 64 + laned) * 8 + (quad & 1) * 4] = d;
  }
  // stage 3: msg^T tiles
  f32x4 acc3[8];
#pragma unroll
  for (int rt = 0; rt < 8; ++rt) acc3[rt] = (f32x4){0.f, 0.f, 0.f, 0.f};
#pragma unroll
  for (int ks = 0; ks < 8; ++ks) {
    bf16x8 bfrag = *(const bf16x8*)&vB[((w * 8 + ks) * 64 + l) * 8];
#pragma unroll
    for (int rt = 0; rt < 8; ++rt) {
      bf16x8 afrag = *(const bf16x8*)&W3p[((size_t)(rt * 8 + ks) * 64 + l) * 8];
      acc3[rt] = __builtin_amdgcn_mfma_f32_16x16x32_bf16(afrag, bfrag, acc3[rt], 0, 0, 0);
    }
  }
  // epilogue: lane holds msg[edge = w*16+col][o = rt*16 + quad*4 + reg]
  const int tg = tIdx[w * 16 + col];
  if (tg >= 0) {
    float* ap = agg + (size_t)tg * DD;
#pragma unroll
    for (int rt = 0; rt < 8; ++rt) {
      float4 b3v = *(const float4*)(b3 + rt * 16 + quad * 4);
      const int o = rt * 16 + quad * 4;
      atomicAdd(ap + o + 0, acc3[rt][0] + b3v.x);
      atomicAdd(ap + o + 1, acc3[rt][1] + b3v.y);
      atomicAdd(ap + o + 2, acc3[rt][2] + b3v.z);
      atomicAdd(ap + o + 3, acc3[rt][3] + b3v.w);
    }
  }
}

__global__ void scale_agg_kernel(float* agg, const float* __restrict__ inv_counts) {
  int idx = blockIdx.x * blockDim.x + threadIdx.x;
  if (idx >= NN * DD) return;
  agg[idx] *= inv_counts[idx >> 7];
}

__global__ void gru_gate_kernel(const float* __restrict__ gi, const float* __restrict__ gh,
                                float* __restrict__ h) {
  int idx = blockIdx.x * blockDim.x + threadIdx.x;
  if (idx >= NN * DD) return;
  int n = idx >> 7, j = idx & (DD - 1);
  const float* gir = gi + (size_t)n * (3 * DD);
  const float* ghr = gh + (size_t)n * (3 * DD);
  float r = fast_sigmoid(gir[j] + ghr[j]);
  float z = fast_sigmoid(gir[DD + j] + ghr[DD + j]);
  float nv = fast_tanh(gir[2 * DD + j] + r * ghr[2 * DD + j]);
  float hv = h[idx];
  h[idx] = (1.0f - z) * nv + z * hv;
}

__global__ __launch_bounds__(256) void dec3_kernel(const float* __restrict__ o2,
                                                   const float* __restrict__ W3,
                                                   const float* __restrict__ b3,
                                                   float* __restrict__ out) {
  int lane = threadIdx.x & 63;
  int n = blockIdx.x * 4 + (threadIdx.x >> 6);
  if (n >= NN) return;
  const float* r = o2 + (size_t)n * HH;
  float p = 0.f;
#pragma unroll
  for (int i = 0; i < 4; ++i) p = fmaf(r[lane + 64 * i], W3[lane + 64 * i], p);
  for (int off = 32; off > 0; off >>= 1) p += __shfl_down(p, off);
  if (lane == 0) out[n] = p + b3[0];
}

extern "C" void kernel_launch(void* const* d_in, const int* in_sizes, int n_in,
                              void* d_out, int out_size, void* d_ws, size_t ws_size,
                              hipStream_t stream) {
  const float* x      = (const float*)d_in[0];
  const int*   ei     = (const int*)d_in[1];
  const float* enc_W  = (const float*)d_in[2];
  const float* enc_b  = (const float*)d_in[3];
  const float* msg_W1 = (const float*)d_in[4];
  const float* msg_b1 = (const float*)d_in[5];
  const float* msg_W2 = (const float*)d_in[6];
  const float* msg_b2 = (const float*)d_in[7];
  const float* msg_W3 = (const float*)d_in[8];
  const float* msg_b3 = (const float*)d_in[9];
  const float* gWih   = (const float*)d_in[10];
  const float* gWhh   = (const float*)d_in[11];
  const float* gbih   = (const float*)d_in[12];
  const float* gbhh   = (const float*)d_in[13];
  const float* dW1    = (const float*)d_in[14];
  const float* db1    = (const float*)d_in[15];
  const float* dW2    = (const float*)d_in[16];
  const float* db2    = (const float*)d_in[17];
  const float* dW3    = (const float*)d_in[18];
  const float* db3    = (const float*)d_in[19];
  float* out = (float*)d_out;

  float* ws = (float*)d_ws;
  float* counts = ws;                                 // N
  float* h      = ws + NN;                            // 128N
  float* agg    = h + (size_t)NN * DD;                // 128N
  float* R      = agg + (size_t)NN * DD;              // 768N shared scratch
  float* Pt = R;                                      // 256N
  float* Ps = R + (size_t)NN * HH;                    // 256N..512N
  float* gi = R;                                      // alias (P dead by then)
  float* gh = R + (size_t)NN * 3 * DD;
  float* o1 = R;                                      // alias (gi dead by then)
  float* o2 = R + (size_t)NN * HH;
  // bf16 weight packs live in the R+512N..768N window: dead Pt/Ps-era space,
  // consumed by edge_kernel, overwritten later by gh (which is fine — repacked
  // each layer).
  ushort_t* W2pk = (ushort_t*)(R + (size_t)512 * NN);   // 128 KiB
  ushort_t* W3pk = W2pk + (size_t)HH * HH;              // 64 KiB

  const int* esrc = ei;        // edge_index[0] = x_j source
  const int* etgt = ei + NE;   // edge_index[1] = aggregation bucket

  counts_init_kernel<<<(NN + 255) / 256, 256, 0, stream>>>(counts);
  counts_accum_kernel<<<(NE + 255) / 256, 256, 0, stream>>>(etgt, counts);
  counts_inv_kernel<<<(NN + 255) / 256, 256, 0, stream>>>(counts);
  encoder_kernel<<<(NN * DD + 255) / 256, 256, 0, stream>>>(x, enc_W, enc_b, h);

  dim3 gP((NN + 63) / 64, 2);   // NO=256
  dim3 gG((NN + 63) / 64, 3);   // NO=384
  for (int l = 0; l < NLAYERS; ++l) {
    const float* W1 = msg_W1 + (size_t)l * 2 * DD * HH;
    gemm_kernel<DD, false><<<gP, 256, 0, stream>>>(h, W1, msg_b1 + l * HH, Pt, NN, HH);
    gemm_kernel<DD, false><<<gP, 256, 0, stream>>>(h, W1 + (size_t)DD * HH, nullptr, Ps, NN, HH);
    pack_weight_kernel<<<(16 * 8 * 64 + 255) / 256, 256, 0, stream>>>(
        msg_W2 + (size_t)l * HH * HH, W2pk, HH, 16 * 8);
    pack_weight_kernel<<<(8 * 8 * 64 + 255) / 256, 256, 0, stream>>>(
        msg_W3 + (size_t)l * HH * DD, W3pk, DD, 8 * 8);
    hipMemsetAsync(agg, 0, (size_t)NN * DD * sizeof(float), stream);
    edge_kernel<<<(ET + 63) / 64, 256, 0, stream>>>(
        esrc, etgt, Pt, Ps, W2pk, msg_b2 + (size_t)l * HH,
        W3pk, msg_b3 + (size_t)l * DD, agg);
    scale_agg_kernel<<<(NN * DD + 255) / 256, 256, 0, stream>>>(agg, counts);
    gemm_kernel<DD, false><<<gG, 256, 0, stream>>>(
        agg, gWih + (size_t)l * DD * 3 * DD, gbih + (size_t)l * 3 * DD, gi, NN, 3 * DD);
    gemm_kernel<DD, false><<<gG, 256, 0, stream>>>(
        h, gWhh + (size_t)l * DD * 3 * DD, gbhh + (size_t)l * 3 * DD, gh, NN, 3 * DD);
    gru_gate_kernel<<<(NN * DD + 255) / 256, 256, 0, stream>>>(gi, gh, h);
  }
  gemm_kernel<DD, true><<<gP, 256, 0, stream>>>(h, dW1, db1, o1, NN, HH);
  gemm_kernel<HH, true><<<gP, 256, 0, stream>>>(o1, dW2, db2, o2, NN, HH);
  dec3_kernel<<<NN / 4, 256, 0, stream>>>(o2, dW3, db3, out);
}

// Round 3
// 4744.482 us; speedup vs baseline: 2.1009x; 1.4822x over previous
//
#include <hip/hip_runtime.h>
#include <math.h>

#define NN 50000
#define IN_DIM 16
#define DD 128
#define HH 256
#define NE 800000
#define NLAYERS 3
#define ET (NE + NN)

typedef unsigned short ushort_t;
typedef unsigned int uint_t;
typedef __attribute__((ext_vector_type(8))) short bf16x8;   // 8 bf16 = 4 VGPRs
typedef __attribute__((ext_vector_type(4))) float f32x4;

__device__ __forceinline__ float fast_tanh(float x) {
  float ax = fabsf(x);
  float e = __expf(2.0f * ax);
  float t = 1.0f - __fdividef(2.0f, e + 1.0f);
  return copysignf(t, x);
}

// branch-free tanh for the edge path: 1 - 2/(e^{2x}+1); inf/0 endpoints are exact
__device__ __forceinline__ float tanh_u(float x) {
  float e = __expf(2.0f * x);
  return 1.0f - __fdividef(2.0f, e + 1.0f);
}

__device__ __forceinline__ float fast_sigmoid(float x) {
  return __fdividef(1.0f, 1.0f + __expf(-x));
}

__device__ __forceinline__ ushort_t f2bf(float f) {  // RNE fp32->bf16
  uint_t u = __float_as_uint(f);
  u += 0x7FFFu + ((u >> 16) & 1u);
  return (ushort_t)(u >> 16);
}

// ---------------- CSR counting sort (built once, reused 3 layers) ----------------

__global__ void deg_kernel(const int* __restrict__ etgt, int* __restrict__ deg) {
  int e = blockIdx.x * blockDim.x + threadIdx.x;
  if (e >= ET) return;
  int tg = (e < NE) ? etgt[e] : (e - NE);
  atomicAdd(&deg[tg], 1);
}

// single-block exclusive scan of deg -> cursor (row starts); also invc = 1/deg
__global__ __launch_bounds__(1024) void scan_kernel(const int* __restrict__ deg,
                                                    int* __restrict__ cursor,
                                                    float* __restrict__ invc) {
  __shared__ int wsum[16];
  __shared__ int carry_s;
  const int t = threadIdx.x;
  const int lane = t & 63, wid = t >> 6;
  if (t == 0) carry_s = 0;
  __syncthreads();
  for (int base = 0; base < NN; base += 1024) {
    int i = base + t;
    int d = (i < NN) ? deg[i] : 0;
    int v = d;
#pragma unroll
    for (int off = 1; off < 64; off <<= 1) {
      int u = __shfl_up(v, off);
      if (lane >= off) v += u;
    }
    if (lane == 63) wsum[wid] = v;
    __syncthreads();
    int woff = 0;
    for (int k = 0; k < wid; ++k) woff += wsum[k];
    int incl = v + woff;
    int carry = carry_s;
    __syncthreads();  // all have read carry_s/wsum
    if (i < NN) {
      cursor[i] = carry + incl - d;
      invc[i] = 1.0f / (float)d;  // d >= 1 (self loop)
    }
    if (t == 1023) carry_s = carry + incl;
    __syncthreads();
  }
}

__global__ void scatter_kernel(const int* __restrict__ esrc, const int* __restrict__ etgt,
                               int* __restrict__ cursor, int* __restrict__ sSrc,
                               int* __restrict__ sTgt) {
  int e = blockIdx.x * blockDim.x + threadIdx.x;
  if (e >= ET) return;
  int s, tg;
  if (e < NE) { s = esrc[e]; tg = etgt[e]; }
  else        { s = e - NE;  tg = s; }
  int pos = atomicAdd(&cursor[tg], 1);
  sSrc[pos] = s;
  sTgt[pos] = tg;
}

// ---------------------------------------------------------------------------------

__global__ void encoder_kernel(const float* __restrict__ x, const float* __restrict__ W,
                               const float* __restrict__ b, float* __restrict__ h) {
  int idx = blockIdx.x * blockDim.x + threadIdx.x;
  if (idx >= NN * DD) return;
  int n = idx >> 7, j = idx & (DD - 1);
  const float* xr = x + n * IN_DIM;
  float acc = b[j];
#pragma unroll
  for (int k = 0; k < IN_DIM; ++k) acc = fmaf(xr[k], W[k * DD + j], acc);
  h[idx] = fast_tanh(acc);
}

// Pack W[K x M] (row-major) into bf16 A-fragment order for u^T = W^T @ v^T:
//   out[((rt*8+ks)*64 + lane)*8 + j] = bf16(W[(ks*32 + (lane>>4)*8 + j)*M + rt*16 + (lane&15)])
__global__ void pack_weight_kernel(const float* __restrict__ W, ushort_t* __restrict__ out,
                                   int M, int ngrp) {
  int tid = blockIdx.x * blockDim.x + threadIdx.x;
  if (tid >= ngrp * 64) return;
  int lane = tid & 63;
  int g = tid >> 6;
  int rt = g >> 3, ks = g & 7;
  int m = rt * 16 + (lane & 15);
  int k0 = ks * 32 + ((lane >> 4) << 3);
  uint4 o;
  uint_t p[4];
#pragma unroll
  for (int d = 0; d < 4; ++d) {
    ushort_t lo = f2bf(W[(size_t)(k0 + 2 * d) * M + m]);
    ushort_t hi = f2bf(W[(size_t)(k0 + 2 * d + 1) * M + m]);
    p[d] = (uint_t)lo | ((uint_t)hi << 16);
  }
  o.x = p[0]; o.y = p[1]; o.z = p[2]; o.w = p[3];
  *(uint4*)(out + (size_t)tid * 8) = o;
}

// C[M x NO] = act(A[M x K] @ B[K x NO] + bias). Block: 64 rows x 128 cols. (fp32 node GEMM)
template <int K, bool TANH>
__global__ __launch_bounds__(256) void gemm_kernel(
    const float* __restrict__ A, const float* __restrict__ B,
    const float* __restrict__ bias, float* __restrict__ C, int M, int NO) {
  constexpr int KP = K + 4;
  __shared__ float As[64 * KP];
  const int t = threadIdx.x;
  const int row0 = blockIdx.x * 64;
  const int j0 = blockIdx.y * 128;
  {
    const int nf4 = K / 4;
    for (int i = t; i < 64 * nf4; i += 256) {
      int r = i / nf4;
      int kc = (i - r * nf4) * 4;
      int row = row0 + r;
      float4 v4 = make_float4(0.f, 0.f, 0.f, 0.f);
      if (row < M) v4 = *(const float4*)(A + (size_t)row * K + kc);
      *(float4*)&As[r * KP + kc] = v4;
    }
  }
  __syncthreads();
  const int te = t >> 5;
  const int tj = t & 31;
  const int jj = j0 + tj * 4;
  float acc[8][4];
#pragma unroll
  for (int i = 0; i < 8; ++i)
#pragma unroll
    for (int j = 0; j < 4; ++j) acc[i][j] = 0.f;
  const float* Bp = B + jj;
  const float* as0 = As + te * 8 * KP;
  for (int k = 0; k < K; k += 4) {
    float wv[4][4];
#pragma unroll
    for (int kk = 0; kk < 4; ++kk) {
      float4 w4 = *(const float4*)(Bp + (size_t)(k + kk) * NO);
      wv[kk][0] = w4.x; wv[kk][1] = w4.y; wv[kk][2] = w4.z; wv[kk][3] = w4.w;
    }
#pragma unroll
    for (int i = 0; i < 8; ++i) {
      float4 a4 = *(const float4*)(as0 + i * KP + k);
      float va[4] = {a4.x, a4.y, a4.z, a4.w};
#pragma unroll
      for (int j = 0; j < 4; ++j) {
        acc[i][j] = fmaf(va[0], wv[0][j], acc[i][j]);
        acc[i][j] = fmaf(va[1], wv[1][j], acc[i][j]);
        acc[i][j] = fmaf(va[2], wv[2][j], acc[i][j]);
        acc[i][j] = fmaf(va[3], wv[3][j], acc[i][j]);
      }
    }
  }
  float bb[4] = {0.f, 0.f, 0.f, 0.f};
  if (bias) {
    float4 b4 = *(const float4*)(bias + jj);
    bb[0] = b4.x; bb[1] = b4.y; bb[2] = b4.z; bb[3] = b4.w;
  }
#pragma unroll
  for (int i = 0; i < 8; ++i) {
    int row = row0 + te * 8 + i;
    if (row < M) {
      float v0 = acc[i][0] + bb[0], v1 = acc[i][1] + bb[1];
      float v2 = acc[i][2] + bb[2], v3 = acc[i][3] + bb[3];
      if (TANH) {
        v0 = fast_tanh(v0); v1 = fast_tanh(v1);
        v2 = fast_tanh(v2); v3 = fast_tanh(v3);
      }
      float4 o; o.x = v0; o.y = v1; o.z = v2; o.w = v3;
      *(float4*)(C + (size_t)row * NO + jj) = o;
    }
  }
}

// MFMA edge kernel over TARGET-SORTED edges. 64 edges/block, 4 waves, wave w owns
// edges [w*16, w*16+16). Transposed compute (activations are B-operands):
//   u^T = tanh(W2^T @ v^T + b2),  msg^T = W3^T @ u^T + b3
// Epilogue: messages -> LDS, block-level segmented reduction over sorted targets,
// one atomicAdd per (run, column) instead of per (edge, column).
__global__ __launch_bounds__(256, 2) void edge_kernel(
    const int* __restrict__ sSrc, const int* __restrict__ sTgt,
    const float* __restrict__ Pt, const float* __restrict__ Ps,
    const ushort_t* __restrict__ W2p, const float* __restrict__ b2,
    const ushort_t* __restrict__ W3p, const float* __restrict__ b3,
    float* __restrict__ agg) {
  __shared__ float vBf[64 * 132];  // 33792 B; low 32 KiB aliased as bf16 frag buffer
  __shared__ int sIdx[64];
  __shared__ int tIdx[64];
  ushort_t* vB = (ushort_t*)vBf;
  const int t = threadIdx.x;
  const int e0 = blockIdx.x * 64;
  if (t < 64) {
    int e = e0 + t;
    int s = 0, tg = -1;
    if (e < ET) { s = sSrc[e]; tg = sTgt[e]; }
    sIdx[t] = s;
    tIdx[t] = tg;
  }
  __syncthreads();
  // stage 1: gather + tanh + bf16 -> vB (B-frag order). thread (el=t&63, c=t>>6)
  {
    const int el = t & 63, c = t >> 6;
    int tg = tIdx[el]; if (tg < 0) tg = 0;
    const int s = sIdx[el];
    const float4* pt = (const float4*)(Pt + (size_t)tg * HH + c * 64);
    const float4* ps = (const float4*)(Ps + (size_t)s * HH + c * 64);
    const int ct = el >> 4, mr = el & 15;
#pragma unroll
    for (int g = 0; g < 8; ++g) {
      float4 a0 = pt[2 * g], a1 = pt[2 * g + 1];
      float4 b0 = ps[2 * g], b1 = ps[2 * g + 1];
      float f[8] = {a0.x + b0.x, a0.y + b0.y, a0.z + b0.z, a0.w + b0.w,
                    a1.x + b1.x, a1.y + b1.y, a1.z + b1.z, a1.w + b1.w};
      uint4 o;
      uint_t p[4];
#pragma unroll
      for (int d = 0; d < 4; ++d) {
        ushort_t lo = f2bf(tanh_u(f[2 * d]));
        ushort_t hi = f2bf(tanh_u(f[2 * d + 1]));
        p[d] = (uint_t)lo | ((uint_t)hi << 16);
      }
      o.x = p[0]; o.y = p[1]; o.z = p[2]; o.w = p[3];
      const int ks = c * 2 + (g >> 2);
      const int quad = g & 3;
      *(uint4*)&vB[((ct * 8 + ks) * 64 + quad * 16 + mr) * 8] = o;
    }
  }
  __syncthreads();
  const int w = t >> 6, l = t & 63;
  const int quad = l >> 4, col = l & 15;
  // stage 2: u^T tiles (wave-private)
  f32x4 acc[16];
#pragma unroll
  for (int rt = 0; rt < 16; ++rt) acc[rt] = (f32x4){0.f, 0.f, 0.f, 0.f};
#pragma unroll
  for (int ks = 0; ks < 8; ++ks) {
    bf16x8 bfrag = *(const bf16x8*)&vB[((w * 8 + ks) * 64 + l) * 8];
#pragma unroll
    for (int rt = 0; rt < 16; ++rt) {
      bf16x8 afrag = *(const bf16x8*)&W2p[((size_t)(rt * 8 + ks) * 64 + l) * 8];
      acc[rt] = __builtin_amdgcn_mfma_f32_16x16x32_bf16(afrag, bfrag, acc[rt], 0, 0, 0);
    }
  }
  // bias + tanh + write u back into vB (B-frag order), wave-private region
#pragma unroll
  for (int rt = 0; rt < 16; ++rt) {
    float4 bb = *(const float4*)(b2 + rt * 16 + quad * 4);
    float u0 = tanh_u(acc[rt][0] + bb.x);
    float u1 = tanh_u(acc[rt][1] + bb.y);
    float u2 = tanh_u(acc[rt][2] + bb.z);
    float u3 = tanh_u(acc[rt][3] + bb.w);
    uint2 d;
    d.x = (uint_t)f2bf(u0) | ((uint_t)f2bf(u1) << 16);
    d.y = (uint_t)f2bf(u2) | ((uint_t)f2bf(u3) << 16);
    const int ks2 = rt >> 1;
    const int laned = ((rt & 1) * 2 + (quad >> 1)) * 16 + col;
    *(uint2*)&vB[((w * 8 + ks2) * 64 + laned) * 8 + (quad & 1) * 4] = d;
  }
  // stage 3: msg^T tiles
  f32x4 acc3[8];
#pragma unroll
  for (int rt = 0; rt < 8; ++rt) acc3[rt] = (f32x4){0.f, 0.f, 0.f, 0.f};
#pragma unroll
  for (int ks = 0; ks < 8; ++ks) {
    bf16x8 bfrag = *(const bf16x8*)&vB[((w * 8 + ks) * 64 + l) * 8];
#pragma unroll
    for (int rt = 0; rt < 8; ++rt) {
      bf16x8 afrag = *(const bf16x8*)&W3p[((size_t)(rt * 8 + ks) * 64 + l) * 8];
      acc3[rt] = __builtin_amdgcn_mfma_f32_16x16x32_bf16(afrag, bfrag, acc3[rt], 0, 0, 0);
    }
  }
  __syncthreads();  // all waves done reading vB before fp32 overwrite
  // write msg (+b3) to vBf[edge][o], padded stride 132
  {
    float* row = vBf + (w * 16 + col) * 132;
#pragma unroll
    for (int rt = 0; rt < 8; ++rt) {
      float4 b3v = *(const float4*)(b3 + rt * 16 + quad * 4);
      float4 o4;
      o4.x = acc3[rt][0] + b3v.x;
      o4.y = acc3[rt][1] + b3v.y;
      o4.z = acc3[rt][2] + b3v.z;
      o4.w = acc3[rt][3] + b3v.w;
      *(float4*)(row + rt * 16 + quad * 4) = o4;
    }
  }
  __syncthreads();
  // segmented reduction: thread t owns column j = t&127 over edges [h*32,(h+1)*32)
  {
    const int j = t & 127;
    const int hb = t >> 7;
    const float* colp = vBf + j;
    int cur = tIdx[hb * 32];
    float a = 0.f;
    for (int e = hb * 32; e < hb * 32 + 32; ++e) {  // tIdx[e] wave-uniform -> no divergence
      int tg = tIdx[e];
      if (tg != cur) {
        if (cur >= 0) atomicAdd(&agg[(size_t)cur * DD + j], a);
        a = 0.f;
        cur = tg;
      }
      a += colp[e * 132];
    }
    if (cur >= 0) atomicAdd(&agg[(size_t)cur * DD + j], a);
  }
}

__global__ void scale_agg_kernel(float* agg, const float* __restrict__ inv_counts) {
  int idx = blockIdx.x * blockDim.x + threadIdx.x;
  if (idx >= NN * DD) return;
  agg[idx] *= inv_counts[idx >> 7];
}

__global__ void gru_gate_kernel(const float* __restrict__ gi, const float* __restrict__ gh,
                                float* __restrict__ h) {
  int idx = blockIdx.x * blockDim.x + threadIdx.x;
  if (idx >= NN * DD) return;
  int n = idx >> 7, j = idx & (DD - 1);
  const float* gir = gi + (size_t)n * (3 * DD);
  const float* ghr = gh + (size_t)n * (3 * DD);
  float r = fast_sigmoid(gir[j] + ghr[j]);
  float z = fast_sigmoid(gir[DD + j] + ghr[DD + j]);
  float nv = fast_tanh(gir[2 * DD + j] + r * ghr[2 * DD + j]);
  float hv = h[idx];
  h[idx] = (1.0f - z) * nv + z * hv;
}

__global__ __launch_bounds__(256) void dec3_kernel(const float* __restrict__ o2,
                                                   const float* __restrict__ W3,
                                                   const float* __restrict__ b3,
                                                   float* __restrict__ out) {
  int lane = threadIdx.x & 63;
  int n = blockIdx.x * 4 + (threadIdx.x >> 6);
  if (n >= NN) return;
  const float* r = o2 + (size_t)n * HH;
  float p = 0.f;
#pragma unroll
  for (int i = 0; i < 4; ++i) p = fmaf(r[lane + 64 * i], W3[lane + 64 * i], p);
  for (int off = 32; off > 0; off >>= 1) p += __shfl_down(p, off);
  if (lane == 0) out[n] = p + b3[0];
}

extern "C" void kernel_launch(void* const* d_in, const int* in_sizes, int n_in,
                              void* d_out, int out_size, void* d_ws, size_t ws_size,
                              hipStream_t stream) {
  const float* x      = (const float*)d_in[0];
  const int*   ei     = (const int*)d_in[1];
  const float* enc_W  = (const float*)d_in[2];
  const float* enc_b  = (const float*)d_in[3];
  const float* msg_W1 = (const float*)d_in[4];
  const float* msg_b1 = (const float*)d_in[5];
  const float* msg_W2 = (const float*)d_in[6];
  const float* msg_b2 = (const float*)d_in[7];
  const float* msg_W3 = (const float*)d_in[8];
  const float* msg_b3 = (const float*)d_in[9];
  const float* gWih   = (const float*)d_in[10];
  const float* gWhh   = (const float*)d_in[11];
  const float* gbih   = (const float*)d_in[12];
  const float* gbhh   = (const float*)d_in[13];
  const float* dW1    = (const float*)d_in[14];
  const float* db1    = (const float*)d_in[15];
  const float* dW2    = (const float*)d_in[16];
  const float* db2    = (const float*)d_in[17];
  const float* dW3    = (const float*)d_in[18];
  const float* db3    = (const float*)d_in[19];
  float* out = (float*)d_out;

  float* ws = (float*)d_ws;
  float* invc = ws;                                   // N  (1/deg incl self loop)
  float* h    = ws + NN;                              // 128N
  float* agg  = h + (size_t)NN * DD;                  // 128N
  float* R    = agg + (size_t)NN * DD;                // 768N shared scratch
  float* Pt = R;                                      // 256N
  float* Ps = R + (size_t)NN * HH;                    // 256N..512N
  float* gi = R;                                      // alias (P dead by then)
  float* gh = R + (size_t)NN * 3 * DD;
  float* o1 = R;                                      // alias (gi dead by then)
  float* o2 = R + (size_t)NN * HH;
  ushort_t* W2pk = (ushort_t*)(R + (size_t)512 * NN); // 128 KiB (dead P-window)
  ushort_t* W3pk = W2pk + (size_t)HH * HH;            // 64 KiB
  // CSR sort arrays beyond the R region (+7.2 MB): persist across all layers
  int* deg    = (int*)(R + (size_t)768 * NN);         // N
  int* cursor = deg + NN;                             // N
  int* sSrc   = cursor + NN;                          // ET
  int* sTgt   = sSrc + ET;                            // ET

  const int* esrc = ei;        // edge_index[0] = x_j source
  const int* etgt = ei + NE;   // edge_index[1] = aggregation bucket

  // ---- build target-sorted edge list (once; reused 3 layers) ----
  hipMemsetAsync(deg, 0, NN * sizeof(int), stream);
  deg_kernel<<<(ET + 255) / 256, 256, 0, stream>>>(etgt, deg);
  scan_kernel<<<1, 1024, 0, stream>>>(deg, cursor, invc);
  scatter_kernel<<<(ET + 255) / 256, 256, 0, stream>>>(esrc, etgt, cursor, sSrc, sTgt);

  encoder_kernel<<<(NN * DD + 255) / 256, 256, 0, stream>>>(x, enc_W, enc_b, h);

  dim3 gP((NN + 63) / 64, 2);   // NO=256
  dim3 gG((NN + 63) / 64, 3);   // NO=384
  for (int l = 0; l < NLAYERS; ++l) {
    const float* W1 = msg_W1 + (size_t)l * 2 * DD * HH;
    gemm_kernel<DD, false><<<gP, 256, 0, stream>>>(h, W1, msg_b1 + l * HH, Pt, NN, HH);
    gemm_kernel<DD, false><<<gP, 256, 0, stream>>>(h, W1 + (size_t)DD * HH, nullptr, Ps, NN, HH);
    pack_weight_kernel<<<(16 * 8 * 64 + 255) / 256, 256, 0, stream>>>(
        msg_W2 + (size_t)l * HH * HH, W2pk, HH, 16 * 8);
    pack_weight_kernel<<<(8 * 8 * 64 + 255) / 256, 256, 0, stream>>>(
        msg_W3 + (size_t)l * HH * DD, W3pk, DD, 8 * 8);
    hipMemsetAsync(agg, 0, (size_t)NN * DD * sizeof(float), stream);
    edge_kernel<<<(ET + 63) / 64, 256, 0, stream>>>(
        sSrc, sTgt, Pt, Ps, W2pk, msg_b2 + (size_t)l * HH,
        W3pk, msg_b3 + (size_t)l * DD, agg);
    scale_agg_kernel<<<(NN * DD + 255) / 256, 256, 0, stream>>>(agg, invc);
    gemm_kernel<DD, false><<<gG, 256, 0, stream>>>(
        agg, gWih + (size_t)l * DD * 3 * DD, gbih + (size_t)l * 3 * DD, gi, NN, 3 * DD);
    gemm_kernel<DD, false><<<gG, 256, 0, stream>>>(
        h, gWhh + (size_t)l * DD * 3 * DD, gbhh + (size_t)l * 3 * DD, gh, NN, 3 * DD);
    gru_gate_kernel<<<(NN * DD + 255) / 256, 256, 0, stream>>>(gi, gh, h);
  }
  gemm_kernel<DD, true><<<gP, 256, 0, stream>>>(h, dW1, db1, o1, NN, HH);
  gemm_kernel<HH, true><<<gP, 256, 0, stream>>>(o1, dW2, db2, o2, NN, HH);
  dec3_kernel<<<NN / 4, 256, 0, stream>>>(o2, dW3, db3, out);
}

// Round 4
// 4196.616 us; speedup vs baseline: 2.3752x; 1.1305x over previous
//
#include <hip/hip_runtime.h>
#include <math.h>

#define NN 50000
#define IN_DIM 16
#define DD 128
#define HH 256
#define NE 800000
#define NLAYERS 3
#define ET (NE + NN)

typedef unsigned short ushort_t;
typedef unsigned int uint_t;
typedef __attribute__((ext_vector_type(8))) short bf16x8;   // 8 bf16 = 4 VGPRs
typedef __attribute__((ext_vector_type(4))) float f32x4;

__device__ __forceinline__ float fast_tanh(float x) {
  float ax = fabsf(x);
  float e = __expf(2.0f * ax);
  float t = 1.0f - __fdividef(2.0f, e + 1.0f);
  return copysignf(t, x);
}

// branch-free tanh for the edge path: 1 - 2/(e^{2x}+1); inf/0 endpoints are exact
__device__ __forceinline__ float tanh_u(float x) {
  float e = __expf(2.0f * x);
  return 1.0f - __fdividef(2.0f, e + 1.0f);
}

__device__ __forceinline__ float fast_sigmoid(float x) {
  return __fdividef(1.0f, 1.0f + __expf(-x));
}

__device__ __forceinline__ ushort_t f2bf(float f) {  // RNE fp32->bf16
  uint_t u = __float_as_uint(f);
  u += 0x7FFFu + ((u >> 16) & 1u);
  return (ushort_t)(u >> 16);
}

__device__ __forceinline__ float bflo(uint_t d) { return __uint_as_float(d << 16); }
__device__ __forceinline__ float bfhi(uint_t d) { return __uint_as_float(d & 0xFFFF0000u); }

// ---------------- CSR counting sort (built once, reused 3 layers) ----------------

__global__ void deg_kernel(const int* __restrict__ etgt, int* __restrict__ deg) {
  int e = blockIdx.x * blockDim.x + threadIdx.x;
  if (e >= ET) return;
  int tg = (e < NE) ? etgt[e] : (e - NE);
  atomicAdd(&deg[tg], 1);
}

// single-block exclusive scan of deg -> cursor (row starts); also invc = 1/deg
__global__ __launch_bounds__(1024) void scan_kernel(const int* __restrict__ deg,
                                                    int* __restrict__ cursor,
                                                    float* __restrict__ invc) {
  __shared__ int wsum[16];
  __shared__ int carry_s;
  const int t = threadIdx.x;
  const int lane = t & 63, wid = t >> 6;
  if (t == 0) carry_s = 0;
  __syncthreads();
  for (int base = 0; base < NN; base += 1024) {
    int i = base + t;
    int d = (i < NN) ? deg[i] : 0;
    int v = d;
#pragma unroll
    for (int off = 1; off < 64; off <<= 1) {
      int u = __shfl_up(v, off);
      if (lane >= off) v += u;
    }
    if (lane == 63) wsum[wid] = v;
    __syncthreads();
    int woff = 0;
    for (int k = 0; k < wid; ++k) woff += wsum[k];
    int incl = v + woff;
    int carry = carry_s;
    __syncthreads();  // all have read carry_s/wsum
    if (i < NN) {
      cursor[i] = carry + incl - d;
      invc[i] = 1.0f / (float)d;  // d >= 1 (self loop)
    }
    if (t == 1023) carry_s = carry + incl;
    __syncthreads();
  }
}

__global__ void scatter_kernel(const int* __restrict__ esrc, const int* __restrict__ etgt,
                               int* __restrict__ cursor, int* __restrict__ sSrc,
                               int* __restrict__ sTgt) {
  int e = blockIdx.x * blockDim.x + threadIdx.x;
  if (e >= ET) return;
  int s, tg;
  if (e < NE) { s = esrc[e]; tg = etgt[e]; }
  else        { s = e - NE;  tg = s; }
  int pos = atomicAdd(&cursor[tg], 1);
  sSrc[pos] = s;
  sTgt[pos] = tg;
}

// ---------------------------------------------------------------------------------

__global__ void encoder_kernel(const float* __restrict__ x, const float* __restrict__ W,
                               const float* __restrict__ b, float* __restrict__ h) {
  int idx = blockIdx.x * blockDim.x + threadIdx.x;
  if (idx >= NN * DD) return;
  int n = idx >> 7, j = idx & (DD - 1);
  const float* xr = x + n * IN_DIM;
  float acc = b[j];
#pragma unroll
  for (int k = 0; k < IN_DIM; ++k) acc = fmaf(xr[k], W[k * DD + j], acc);
  h[idx] = fast_tanh(acc);
}

// Pack W[K x M] (row-major) into bf16 A-fragment order for u^T = W^T @ v^T:
//   out[((rt*8+ks)*64 + lane)*8 + j] = bf16(W[(ks*32 + (lane>>4)*8 + j)*M + rt*16 + (lane&15)])
__global__ void pack_weight_kernel(const float* __restrict__ W, ushort_t* __restrict__ out,
                                   int M, int ngrp) {
  int tid = blockIdx.x * blockDim.x + threadIdx.x;
  if (tid >= ngrp * 64) return;
  int lane = tid & 63;
  int g = tid >> 6;
  int rt = g >> 3, ks = g & 7;
  int m = rt * 16 + (lane & 15);
  int k0 = ks * 32 + ((lane >> 4) << 3);
  uint4 o;
  uint_t p[4];
#pragma unroll
  for (int d = 0; d < 4; ++d) {
    ushort_t lo = f2bf(W[(size_t)(k0 + 2 * d) * M + m]);
    ushort_t hi = f2bf(W[(size_t)(k0 + 2 * d + 1) * M + m]);
    p[d] = (uint_t)lo | ((uint_t)hi << 16);
  }
  o.x = p[0]; o.y = p[1]; o.z = p[2]; o.w = p[3];
  *(uint4*)(out + (size_t)tid * 8) = o;
}

// C[M x NO] = act(A[M x K] @ B[K x NO] + bias). Block: 64 rows x 128 cols.
// fp32 compute; OBF16 stores bf16 (ushort) output instead of fp32.
template <int K, bool TANH, bool OBF16>
__global__ __launch_bounds__(256) void gemm_kernel(
    const float* __restrict__ A, const float* __restrict__ B,
    const float* __restrict__ bias, void* __restrict__ Cv, int M, int NO) {
  constexpr int KP = K + 4;
  __shared__ float As[64 * KP];
  const int t = threadIdx.x;
  const int row0 = blockIdx.x * 64;
  const int j0 = blockIdx.y * 128;
  {
    const int nf4 = K / 4;
    for (int i = t; i < 64 * nf4; i += 256) {
      int r = i / nf4;
      int kc = (i - r * nf4) * 4;
      int row = row0 + r;
      float4 v4 = make_float4(0.f, 0.f, 0.f, 0.f);
      if (row < M) v4 = *(const float4*)(A + (size_t)row * K + kc);
      *(float4*)&As[r * KP + kc] = v4;
    }
  }
  __syncthreads();
  const int te = t >> 5;
  const int tj = t & 31;
  const int jj = j0 + tj * 4;
  float acc[8][4];
#pragma unroll
  for (int i = 0; i < 8; ++i)
#pragma unroll
    for (int j = 0; j < 4; ++j) acc[i][j] = 0.f;
  const float* Bp = B + jj;
  const float* as0 = As + te * 8 * KP;
  for (int k = 0; k < K; k += 4) {
    float wv[4][4];
#pragma unroll
    for (int kk = 0; kk < 4; ++kk) {
      float4 w4 = *(const float4*)(Bp + (size_t)(k + kk) * NO);
      wv[kk][0] = w4.x; wv[kk][1] = w4.y; wv[kk][2] = w4.z; wv[kk][3] = w4.w;
    }
#pragma unroll
    for (int i = 0; i < 8; ++i) {
      float4 a4 = *(const float4*)(as0 + i * KP + k);
      float va[4] = {a4.x, a4.y, a4.z, a4.w};
#pragma unroll
      for (int j = 0; j < 4; ++j) {
        acc[i][j] = fmaf(va[0], wv[0][j], acc[i][j]);
        acc[i][j] = fmaf(va[1], wv[1][j], acc[i][j]);
        acc[i][j] = fmaf(va[2], wv[2][j], acc[i][j]);
        acc[i][j] = fmaf(va[3], wv[3][j], acc[i][j]);
      }
    }
  }
  float bb[4] = {0.f, 0.f, 0.f, 0.f};
  if (bias) {
    float4 b4 = *(const float4*)(bias + jj);
    bb[0] = b4.x; bb[1] = b4.y; bb[2] = b4.z; bb[3] = b4.w;
  }
#pragma unroll
  for (int i = 0; i < 8; ++i) {
    int row = row0 + te * 8 + i;
    if (row < M) {
      float v0 = acc[i][0] + bb[0], v1 = acc[i][1] + bb[1];
      float v2 = acc[i][2] + bb[2], v3 = acc[i][3] + bb[3];
      if (TANH) {
        v0 = fast_tanh(v0); v1 = fast_tanh(v1);
        v2 = fast_tanh(v2); v3 = fast_tanh(v3);
      }
      if (OBF16) {
        ushort_t* Cr = (ushort_t*)Cv + (size_t)row * NO + jj;
        uint2 dp;
        dp.x = (uint_t)f2bf(v0) | ((uint_t)f2bf(v1) << 16);
        dp.y = (uint_t)f2bf(v2) | ((uint_t)f2bf(v3) << 16);
        *(uint2*)Cr = dp;
      } else {
        float4 o; o.x = v0; o.y = v1; o.z = v2; o.w = v3;
        *(float4*)((float*)Cv + (size_t)row * NO + jj) = o;
      }
    }
  }
}

// MFMA edge kernel over TARGET-SORTED edges, bf16 Pt/Ps. 64 edges/block, 4 waves,
// wave w owns edges [w*16, w*16+16). Transposed compute (activations B-operands):
//   u^T = tanh(W2^T @ v^T + b2),  msg^T = W3^T @ u^T + b3
// Epilogue: messages -> LDS (stride 128, wave-aligned), block segmented reduction
// over sorted targets, one atomicAdd per (run, column).
__global__ __launch_bounds__(256, 3) void edge_kernel(
    const int* __restrict__ sSrc, const int* __restrict__ sTgt,
    const ushort_t* __restrict__ Ptb, const ushort_t* __restrict__ Psb,
    const ushort_t* __restrict__ W2p, const float* __restrict__ b2,
    const ushort_t* __restrict__ W3p, const float* __restrict__ b3,
    float* __restrict__ agg) {
  __shared__ float vBf[64 * 128];  // 32 KiB; aliased as bf16 frag buffer
  __shared__ int sIdx[64];
  __shared__ int tIdx[64];
  ushort_t* vB = (ushort_t*)vBf;
  const int t = threadIdx.x;
  const int e0 = blockIdx.x * 64;
  if (t < 64) {
    int e = e0 + t;
    int s = 0, tg = -1;
    if (e < ET) { s = sSrc[e]; tg = sTgt[e]; }
    sIdx[t] = s;
    tIdx[t] = tg;
  }
  __syncthreads();
  // stage 1: bf16 gather + tanh -> vB (B-frag order). thread (el=t&63, c=t>>6)
  {
    const int el = t & 63, c = t >> 6;
    int tg = tIdx[el]; if (tg < 0) tg = 0;
    const int s = sIdx[el];
    const uint4* pt = (const uint4*)(Ptb + (size_t)tg * HH + c * 64);
    const uint4* ps = (const uint4*)(Psb + (size_t)s * HH + c * 64);
    const int ct = el >> 4, mr = el & 15;
#pragma unroll
    for (int g = 0; g < 8; ++g) {
      uint4 av = pt[g];
      uint4 bv = ps[g];
      uint_t ad[4] = {av.x, av.y, av.z, av.w};
      uint_t bd[4] = {bv.x, bv.y, bv.z, bv.w};
      uint_t p[4];
#pragma unroll
      for (int d = 0; d < 4; ++d) {
        float flo = bflo(ad[d]) + bflo(bd[d]);
        float fhi = bfhi(ad[d]) + bfhi(bd[d]);
        ushort_t lo = f2bf(tanh_u(flo));
        ushort_t hi = f2bf(tanh_u(fhi));
        p[d] = (uint_t)lo | ((uint_t)hi << 16);
      }
      uint4 o;
      o.x = p[0]; o.y = p[1]; o.z = p[2]; o.w = p[3];
      const int ks = c * 2 + (g >> 2);
      const int quad = g & 3;
      *(uint4*)&vB[((ct * 8 + ks) * 64 + quad * 16 + mr) * 8] = o;
    }
  }
  __syncthreads();
  const int w = t >> 6, l = t & 63;
  const int quad = l >> 4, col = l & 15;
  // stage 2: u^T tiles (wave-private)
  f32x4 acc[16];
#pragma unroll
  for (int rt = 0; rt < 16; ++rt) acc[rt] = (f32x4){0.f, 0.f, 0.f, 0.f};
#pragma unroll
  for (int ks = 0; ks < 8; ++ks) {
    bf16x8 bfrag = *(const bf16x8*)&vB[((w * 8 + ks) * 64 + l) * 8];
#pragma unroll
    for (int rt = 0; rt < 16; ++rt) {
      bf16x8 afrag = *(const bf16x8*)&W2p[((size_t)(rt * 8 + ks) * 64 + l) * 8];
      acc[rt] = __builtin_amdgcn_mfma_f32_16x16x32_bf16(afrag, bfrag, acc[rt], 0, 0, 0);
    }
  }
  // bias + tanh + write u back into vB (B-frag order), wave-private region
#pragma unroll
  for (int rt = 0; rt < 16; ++rt) {
    float4 bb = *(const float4*)(b2 + rt * 16 + quad * 4);
    float u0 = tanh_u(acc[rt][0] + bb.x);
    float u1 = tanh_u(acc[rt][1] + bb.y);
    float u2 = tanh_u(acc[rt][2] + bb.z);
    float u3 = tanh_u(acc[rt][3] + bb.w);
    uint2 d;
    d.x = (uint_t)f2bf(u0) | ((uint_t)f2bf(u1) << 16);
    d.y = (uint_t)f2bf(u2) | ((uint_t)f2bf(u3) << 16);
    const int ks2 = rt >> 1;
    const int laned = ((rt & 1) * 2 + (quad >> 1)) * 16 + col;
    *(uint2*)&vB[((w * 8 + ks2) * 64 + laned) * 8 + (quad & 1) * 4] = d;
  }
  // stage 3: msg^T tiles
  f32x4 acc3[8];
#pragma unroll
  for (int rt = 0; rt < 8; ++rt) acc3[rt] = (f32x4){0.f, 0.f, 0.f, 0.f};
#pragma unroll
  for (int ks = 0; ks < 8; ++ks) {
    bf16x8 bfrag = *(const bf16x8*)&vB[((w * 8 + ks) * 64 + l) * 8];
#pragma unroll
    for (int rt = 0; rt < 8; ++rt) {
      bf16x8 afrag = *(const bf16x8*)&W3p[((size_t)(rt * 8 + ks) * 64 + l) * 8];
      acc3[rt] = __builtin_amdgcn_mfma_f32_16x16x32_bf16(afrag, bfrag, acc3[rt], 0, 0, 0);
    }
  }
  // write msg (+b3) to vBf[edge][o], stride 128. Wave w's msg rows exactly alias
  // wave w's own (already-consumed) frag region, so no barrier needed here; DS
  // ops from one wave complete in order.
  {
    float* row = vBf + (w * 16 + col) * 128;
#pragma unroll
    for (int rt = 0; rt < 8; ++rt) {
      float4 b3v = *(const float4*)(b3 + rt * 16 + quad * 4);
      float4 o4;
      o4.x = acc3[rt][0] + b3v.x;
      o4.y = acc3[rt][1] + b3v.y;
      o4.z = acc3[rt][2] + b3v.z;
      o4.w = acc3[rt][3] + b3v.w;
      *(float4*)(row + rt * 16 + quad * 4) = o4;
    }
  }
  __syncthreads();
  // segmented reduction: thread t owns column j = t&127 over edges [hb*32,(hb+1)*32)
  {
    const int j = t & 127;
    const int hb = t >> 7;
    const float* colp = vBf + j;
    int cur = tIdx[hb * 32];
    float a = 0.f;
    for (int e = hb * 32; e < hb * 32 + 32; ++e) {  // tIdx[e] wave-uniform -> no divergence
      int tg = tIdx[e];
      if (tg != cur) {
        if (cur >= 0) atomicAdd(&agg[(size_t)cur * DD + j], a);
        a = 0.f;
        cur = tg;
      }
      a += colp[e * 128];
    }
    if (cur >= 0) atomicAdd(&agg[(size_t)cur * DD + j], a);
  }
}

__global__ void scale_agg_kernel(float* agg, const float* __restrict__ inv_counts) {
  int idx = blockIdx.x * blockDim.x + threadIdx.x;
  if (idx >= NN * DD) return;
  agg[idx] *= inv_counts[idx >> 7];
}

__global__ void gru_gate_kernel(const float* __restrict__ gi, const float* __restrict__ gh,
                                float* __restrict__ h) {
  int idx = blockIdx.x * blockDim.x + threadIdx.x;
  if (idx >= NN * DD) return;
  int n = idx >> 7, j = idx & (DD - 1);
  const float* gir = gi + (size_t)n * (3 * DD);
  const float* ghr = gh + (size_t)n * (3 * DD);
  float r = fast_sigmoid(gir[j] + ghr[j]);
  float z = fast_sigmoid(gir[DD + j] + ghr[DD + j]);
  float nv = fast_tanh(gir[2 * DD + j] + r * ghr[2 * DD + j]);
  float hv = h[idx];
  h[idx] = (1.0f - z) * nv + z * hv;
}

__global__ __launch_bounds__(256) void dec3_kernel(const float* __restrict__ o2,
                                                   const float* __restrict__ W3,
                                                   const float* __restrict__ b3,
                                                   float* __restrict__ out) {
  int lane = threadIdx.x & 63;
  int n = blockIdx.x * 4 + (threadIdx.x >> 6);
  if (n >= NN) return;
  const float* r = o2 + (size_t)n * HH;
  float p = 0.f;
#pragma unroll
  for (int i = 0; i < 4; ++i) p = fmaf(r[lane + 64 * i], W3[lane + 64 * i], p);
  for (int off = 32; off > 0; off >>= 1) p += __shfl_down(p, off);
  if (lane == 0) out[n] = p + b3[0];
}

extern "C" void kernel_launch(void* const* d_in, const int* in_sizes, int n_in,
                              void* d_out, int out_size, void* d_ws, size_t ws_size,
                              hipStream_t stream) {
  const float* x      = (const float*)d_in[0];
  const int*   ei     = (const int*)d_in[1];
  const float* enc_W  = (const float*)d_in[2];
  const float* enc_b  = (const float*)d_in[3];
  const float* msg_W1 = (const float*)d_in[4];
  const float* msg_b1 = (const float*)d_in[5];
  const float* msg_W2 = (const float*)d_in[6];
  const float* msg_b2 = (const float*)d_in[7];
  const float* msg_W3 = (const float*)d_in[8];
  const float* msg_b3 = (const float*)d_in[9];
  const float* gWih   = (const float*)d_in[10];
  const float* gWhh   = (const float*)d_in[11];
  const float* gbih   = (const float*)d_in[12];
  const float* gbhh   = (const float*)d_in[13];
  const float* dW1    = (const float*)d_in[14];
  const float* db1    = (const float*)d_in[15];
  const float* dW2    = (const float*)d_in[16];
  const float* db2    = (const float*)d_in[17];
  const float* dW3    = (const float*)d_in[18];
  const float* db3    = (const float*)d_in[19];
  float* out = (float*)d_out;

  float* ws = (float*)d_ws;
  float* invc = ws;                                   // N  (1/deg incl self loop)
  float* h    = ws + NN;                              // 128N
  float* agg  = h + (size_t)NN * DD;                  // 128N
  float* R    = agg + (size_t)NN * DD;                // 768N shared scratch
  // bf16 P arrays: NN*HH ushorts = 128N floats each
  ushort_t* Ptb = (ushort_t*)R;                       // [R, R+128N)
  ushort_t* Psb = (ushort_t*)(R + (size_t)128 * NN);  // [R+128N, R+256N)
  float* gi = R;                                      // alias (P dead by then)
  float* gh = R + (size_t)NN * 3 * DD;
  float* o1 = R;                                      // alias (gi dead by then)
  float* o2 = R + (size_t)NN * HH;
  ushort_t* W2pk = (ushort_t*)(R + (size_t)512 * NN); // 128 KiB (dead window; repacked each layer)
  ushort_t* W3pk = W2pk + (size_t)HH * HH;            // 64 KiB
  // CSR sort arrays beyond the R region (+7.2 MB): persist across all layers
  int* deg    = (int*)(R + (size_t)768 * NN);         // N
  int* cursor = deg + NN;                             // N
  int* sSrc   = cursor + NN;                          // ET
  int* sTgt   = sSrc + ET;                            // ET

  const int* esrc = ei;        // edge_index[0] = x_j source
  const int* etgt = ei + NE;   // edge_index[1] = aggregation bucket

  // ---- build target-sorted edge list (once; reused 3 layers) ----
  hipMemsetAsync(deg, 0, NN * sizeof(int), stream);
  deg_kernel<<<(ET + 255) / 256, 256, 0, stream>>>(etgt, deg);
  scan_kernel<<<1, 1024, 0, stream>>>(deg, cursor, invc);
  scatter_kernel<<<(ET + 255) / 256, 256, 0, stream>>>(esrc, etgt, cursor, sSrc, sTgt);

  encoder_kernel<<<(NN * DD + 255) / 256, 256, 0, stream>>>(x, enc_W, enc_b, h);

  dim3 gP((NN + 63) / 64, 2);   // NO=256
  dim3 gG((NN + 63) / 64, 3);   // NO=384
  for (int l = 0; l < NLAYERS; ++l) {
    const float* W1 = msg_W1 + (size_t)l * 2 * DD * HH;
    gemm_kernel<DD, false, true><<<gP, 256, 0, stream>>>(h, W1, msg_b1 + l * HH, Ptb, NN, HH);
    gemm_kernel<DD, false, true><<<gP, 256, 0, stream>>>(h, W1 + (size_t)DD * HH, nullptr, Psb, NN, HH);
    pack_weight_kernel<<<(16 * 8 * 64 + 255) / 256, 256, 0, stream>>>(
        msg_W2 + (size_t)l * HH * HH, W2pk, HH, 16 * 8);
    pack_weight_kernel<<<(8 * 8 * 64 + 255) / 256, 256, 0, stream>>>(
        msg_W3 + (size_t)l * HH * DD, W3pk, DD, 8 * 8);
    hipMemsetAsync(agg, 0, (size_t)NN * DD * sizeof(float), stream);
    edge_kernel<<<(ET + 63) / 64, 256, 0, stream>>>(
        sSrc, sTgt, Ptb, Psb, W2pk, msg_b2 + (size_t)l * HH,
        W3pk, msg_b3 + (size_t)l * DD, agg);
    scale_agg_kernel<<<(NN * DD + 255) / 256, 256, 0, stream>>>(agg, invc);
    gemm_kernel<DD, false, false><<<gG, 256, 0, stream>>>(
        agg, gWih + (size_t)l * DD * 3 * DD, gbih + (size_t)l * 3 * DD, gi, NN, 3 * DD);
    gemm_kernel<DD, false, false><<<gG, 256, 0, stream>>>(
        h, gWhh + (size_t)l * DD * 3 * DD, gbhh + (size_t)l * 3 * DD, gh, NN, 3 * DD);
    gru_gate_kernel<<<(NN * DD + 255) / 256, 256, 0, stream>>>(gi, gh, h);
  }
  gemm_kernel<DD, true, false><<<gP, 256, 0, stream>>>(h, dW1, db1, o1, NN, HH);
  gemm_kernel<HH, true, false><<<gP, 256, 0, stream>>>(o1, dW2, db2, o2, NN, HH);
  dec3_kernel<<<NN / 4, 256, 0, stream>>>(o2, dW3, db3, out);
}

// Round 5
// 2511.577 us; speedup vs baseline: 3.9687x; 1.6709x over previous
//
#include <hip/hip_runtime.h>
#include <math.h>

#define NN 50000
#define IN_DIM 16
#define DD 128
#define HH 256
#define NE 800000
#define NLAYERS 3
#define ET (NE + NN)

typedef unsigned short ushort_t;
typedef unsigned int uint_t;
typedef __attribute__((ext_vector_type(8))) short bf16x8;   // 8 bf16 = 4 VGPRs
typedef __attribute__((ext_vector_type(4))) float f32x4;

// tanh(x) = 1 - 2/(e^{2x}+1) = 1 - 2*rcp(exp2(x*2*log2e)+1)
// v_exp_f32 + v_rcp_f32 directly (2 quarter-rate + 3 full-rate). ±inf exact.
__device__ __forceinline__ float fast_tanh(float x) {
  float e = __builtin_amdgcn_exp2f(x * 2.88539008177793f);
  float r = __builtin_amdgcn_rcpf(e + 1.0f);
  return fmaf(-2.0f, r, 1.0f);
}

__device__ __forceinline__ float fast_sigmoid(float x) {
  float e = __builtin_amdgcn_exp2f(x * -1.44269504088896f);
  return __builtin_amdgcn_rcpf(e + 1.0f);
}

__device__ __forceinline__ ushort_t f2bf(float f) {  // RNE fp32->bf16
  uint_t u = __float_as_uint(f);
  u += 0x7FFFu + ((u >> 16) & 1u);
  return (ushort_t)(u >> 16);
}

__device__ __forceinline__ float bflo(uint_t d) { return __uint_as_float(d << 16); }
__device__ __forceinline__ float bfhi(uint_t d) { return __uint_as_float(d & 0xFFFF0000u); }

// ---------------- CSR counting sort (built once, reused 3 layers) ----------------

__global__ void deg_kernel(const int* __restrict__ etgt, int* __restrict__ deg) {
  int e = blockIdx.x * blockDim.x + threadIdx.x;
  if (e >= ET) return;
  int tg = (e < NE) ? etgt[e] : (e - NE);
  atomicAdd(&deg[tg], 1);
}

// single-block exclusive scan of deg -> cursor (row starts); also invc = 1/deg
__global__ __launch_bounds__(1024) void scan_kernel(const int* __restrict__ deg,
                                                    int* __restrict__ cursor,
                                                    float* __restrict__ invc) {
  __shared__ int wsum[16];
  __shared__ int carry_s;
  const int t = threadIdx.x;
  const int lane = t & 63, wid = t >> 6;
  if (t == 0) carry_s = 0;
  __syncthreads();
  for (int base = 0; base < NN; base += 1024) {
    int i = base + t;
    int d = (i < NN) ? deg[i] : 0;
    int v = d;
#pragma unroll
    for (int off = 1; off < 64; off <<= 1) {
      int u = __shfl_up(v, off);
      if (lane >= off) v += u;
    }
    if (lane == 63) wsum[wid] = v;
    __syncthreads();
    int woff = 0;
    for (int k = 0; k < wid; ++k) woff += wsum[k];
    int incl = v + woff;
    int carry = carry_s;
    __syncthreads();  // all have read carry_s/wsum
    if (i < NN) {
      cursor[i] = carry + incl - d;
      invc[i] = 1.0f / (float)d;  // d >= 1 (self loop)
    }
    if (t == 1023) carry_s = carry + incl;
    __syncthreads();
  }
}

__global__ void scatter_kernel(const int* __restrict__ esrc, const int* __restrict__ etgt,
                               int* __restrict__ cursor, int* __restrict__ sSrc,
                               int* __restrict__ sTgt) {
  int e = blockIdx.x * blockDim.x + threadIdx.x;
  if (e >= ET) return;
  int s, tg;
  if (e < NE) { s = esrc[e]; tg = etgt[e]; }
  else        { s = e - NE;  tg = s; }
  int pos = atomicAdd(&cursor[tg], 1);
  sSrc[pos] = s;
  sTgt[pos] = tg;
}

// ---------------------------------------------------------------------------------

__global__ void encoder_kernel(const float* __restrict__ x, const float* __restrict__ W,
                               const float* __restrict__ b, float* __restrict__ h) {
  int idx = blockIdx.x * blockDim.x + threadIdx.x;
  if (idx >= NN * DD) return;
  int n = idx >> 7, j = idx & (DD - 1);
  const float* xr = x + n * IN_DIM;
  float acc = b[j];
#pragma unroll
  for (int k = 0; k < IN_DIM; ++k) acc = fmaf(xr[k], W[k * DD + j], acc);
  h[idx] = fast_tanh(acc);
}

// Pack W[K x M] (row-major) into bf16 A-fragment order for u^T = W^T @ v^T:
//   out[((rt*8+ks)*64 + lane)*8 + j] = bf16(W[(ks*32 + (lane>>4)*8 + j)*M + rt*16 + (lane&15)])
__global__ void pack_weight_kernel(const float* __restrict__ W, ushort_t* __restrict__ out,
                                   int M, int ngrp) {
  int tid = blockIdx.x * blockDim.x + threadIdx.x;
  if (tid >= ngrp * 64) return;
  int lane = tid & 63;
  int g = tid >> 6;
  int rt = g >> 3, ks = g & 7;
  int m = rt * 16 + (lane & 15);
  int k0 = ks * 32 + ((lane >> 4) << 3);
  uint4 o;
  uint_t p[4];
#pragma unroll
  for (int d = 0; d < 4; ++d) {
    ushort_t lo = f2bf(W[(size_t)(k0 + 2 * d) * M + m]);
    ushort_t hi = f2bf(W[(size_t)(k0 + 2 * d + 1) * M + m]);
    p[d] = (uint_t)lo | ((uint_t)hi << 16);
  }
  o.x = p[0]; o.y = p[1]; o.z = p[2]; o.w = p[3];
  *(uint4*)(out + (size_t)tid * 8) = o;
}

// C[M x NO] = act(A[M x K] @ B[K x NO] + bias). Block: 64 rows x 128 cols.
// fp32 compute; OBF16 stores bf16 (ushort) output instead of fp32.
template <int K, bool TANH, bool OBF16>
__global__ __launch_bounds__(256) void gemm_kernel(
    const float* __restrict__ A, const float* __restrict__ B,
    const float* __restrict__ bias, void* __restrict__ Cv, int M, int NO) {
  constexpr int KP = K + 4;
  __shared__ float As[64 * KP];
  const int t = threadIdx.x;
  const int row0 = blockIdx.x * 64;
  const int j0 = blockIdx.y * 128;
  {
    const int nf4 = K / 4;
    for (int i = t; i < 64 * nf4; i += 256) {
      int r = i / nf4;
      int kc = (i - r * nf4) * 4;
      int row = row0 + r;
      float4 v4 = make_float4(0.f, 0.f, 0.f, 0.f);
      if (row < M) v4 = *(const float4*)(A + (size_t)row * K + kc);
      *(float4*)&As[r * KP + kc] = v4;
    }
  }
  __syncthreads();
  const int te = t >> 5;
  const int tj = t & 31;
  const int jj = j0 + tj * 4;
  float acc[8][4];
#pragma unroll
  for (int i = 0; i < 8; ++i)
#pragma unroll
    for (int j = 0; j < 4; ++j) acc[i][j] = 0.f;
  const float* Bp = B + jj;
  const float* as0 = As + te * 8 * KP;
  for (int k = 0; k < K; k += 4) {
    float wv[4][4];
#pragma unroll
    for (int kk = 0; kk < 4; ++kk) {
      float4 w4 = *(const float4*)(Bp + (size_t)(k + kk) * NO);
      wv[kk][0] = w4.x; wv[kk][1] = w4.y; wv[kk][2] = w4.z; wv[kk][3] = w4.w;
    }
#pragma unroll
    for (int i = 0; i < 8; ++i) {
      float4 a4 = *(const float4*)(as0 + i * KP + k);
      float va[4] = {a4.x, a4.y, a4.z, a4.w};
#pragma unroll
      for (int j = 0; j < 4; ++j) {
        acc[i][j] = fmaf(va[0], wv[0][j], acc[i][j]);
        acc[i][j] = fmaf(va[1], wv[1][j], acc[i][j]);
        acc[i][j] = fmaf(va[2], wv[2][j], acc[i][j]);
        acc[i][j] = fmaf(va[3], wv[3][j], acc[i][j]);
      }
    }
  }
  float bb[4] = {0.f, 0.f, 0.f, 0.f};
  if (bias) {
    float4 b4 = *(const float4*)(bias + jj);
    bb[0] = b4.x; bb[1] = b4.y; bb[2] = b4.z; bb[3] = b4.w;
  }
#pragma unroll
  for (int i = 0; i < 8; ++i) {
    int row = row0 + te * 8 + i;
    if (row < M) {
      float v0 = acc[i][0] + bb[0], v1 = acc[i][1] + bb[1];
      float v2 = acc[i][2] + bb[2], v3 = acc[i][3] + bb[3];
      if (TANH) {
        v0 = fast_tanh(v0); v1 = fast_tanh(v1);
        v2 = fast_tanh(v2); v3 = fast_tanh(v3);
      }
      if (OBF16) {
        ushort_t* Cr = (ushort_t*)Cv + (size_t)row * NO + jj;
        uint2 dp;
        dp.x = (uint_t)f2bf(v0) | ((uint_t)f2bf(v1) << 16);
        dp.y = (uint_t)f2bf(v2) | ((uint_t)f2bf(v3) << 16);
        *(uint2*)Cr = dp;
      } else {
        float4 o; o.x = v0; o.y = v1; o.z = v2; o.w = v3;
        *(float4*)((float*)Cv + (size_t)row * NO + jj) = o;
      }
    }
  }
}

// MFMA edge kernel, target-sorted edges, bf16 Pt/Ps, WAVE-COOPERATIVE weights:
// 64 edges/block, 4 waves. Wave w computes u-rows [64w,64w+64) (stage 2) and
// msg-rows [32w,32w+32) (stage 3) for ALL 64 edges, so each weight fragment is
// loaded once per BLOCK (not once per wave): afrag traffic 768->192 KB/block.
// v and u live in the same 32 KiB LDS granule buffer (barrier-separated phases);
// msg epilogue uses stride-132 fp32 rows (pad breaks the 16-way bank conflict
// measured in R4: addr = edge*132 + j -> bank varies with edge).
__global__ __launch_bounds__(256, 3) void edge_kernel(
    const int* __restrict__ sSrc, const int* __restrict__ sTgt,
    const ushort_t* __restrict__ Ptb, const ushort_t* __restrict__ Psb,
    const ushort_t* __restrict__ W2p, const float* __restrict__ b2,
    const ushort_t* __restrict__ W3p, const float* __restrict__ b3,
    const float* __restrict__ invc, float* __restrict__ agg) {
  __shared__ float vBf[64 * 132];  // 33792 B; low 32 KiB aliased as bf16 frag buffer
  __shared__ int sIdx[64];
  __shared__ int tIdx[64];
  ushort_t* vB = (ushort_t*)vBf;
  const int t = threadIdx.x;
  const int e0 = blockIdx.x * 64;
  if (t < 64) {
    int e = e0 + t;
    int s = 0, tg = -1;
    if (e < ET) { s = sSrc[e]; tg = sTgt[e]; }
    sIdx[t] = s;
    tIdx[t] = tg;
  }
  __syncthreads();
  // stage 1: bf16 gather + tanh -> vB (B-frag order). thread (el=t&63, c=t>>6)
  // covers k in [c*64, c*64+64). Granule content:
  //   vB[((ct*8+ks)*64 + q*16 + mr)*8 + j] = v[edge=ct*16+mr][k=ks*32+q*8+j]
  {
    const int el = t & 63, c = t >> 6;
    int tg = tIdx[el]; if (tg < 0) tg = 0;
    const int s = sIdx[el];
    const uint4* pt = (const uint4*)(Ptb + (size_t)tg * HH + c * 64);
    const uint4* ps = (const uint4*)(Psb + (size_t)s * HH + c * 64);
    const int ct = el >> 4, mr = el & 15;
#pragma unroll
    for (int g = 0; g < 8; ++g) {
      uint4 av = pt[g];
      uint4 bv = ps[g];
      uint_t ad[4] = {av.x, av.y, av.z, av.w};
      uint_t bd[4] = {bv.x, bv.y, bv.z, bv.w};
      uint_t p[4];
#pragma unroll
      for (int d = 0; d < 4; ++d) {
        float flo = bflo(ad[d]) + bflo(bd[d]);
        float fhi = bfhi(ad[d]) + bfhi(bd[d]);
        ushort_t lo = f2bf(fast_tanh(flo));
        ushort_t hi = f2bf(fast_tanh(fhi));
        p[d] = (uint_t)lo | ((uint_t)hi << 16);
      }
      uint4 o;
      o.x = p[0]; o.y = p[1]; o.z = p[2]; o.w = p[3];
      const int ks = c * 2 + (g >> 2);
      const int quad = g & 3;
      *(uint4*)&vB[((ct * 8 + ks) * 64 + quad * 16 + mr) * 8] = o;
    }
  }
  __syncthreads();
  const int w = t >> 6, l = t & 63;
  const int quad = l >> 4, col = l & 15;
  // stage 2: u^T tile block: wave w does A-rows rt = 4w..4w+3, all 4 edge tiles ct
  f32x4 acc2[4][4];
#pragma unroll
  for (int rp = 0; rp < 4; ++rp)
#pragma unroll
    for (int ct = 0; ct < 4; ++ct) acc2[rp][ct] = (f32x4){0.f, 0.f, 0.f, 0.f};
#pragma unroll
  for (int ks = 0; ks < 8; ++ks) {
    bf16x8 bfrag[4];
#pragma unroll
    for (int ct = 0; ct < 4; ++ct)
      bfrag[ct] = *(const bf16x8*)&vB[((ct * 8 + ks) * 64 + l) * 8];
#pragma unroll
    for (int rp = 0; rp < 4; ++rp) {
      bf16x8 afrag = *(const bf16x8*)&W2p[((size_t)((w * 4 + rp) * 8 + ks) * 64 + l) * 8];
#pragma unroll
      for (int ct = 0; ct < 4; ++ct)
        acc2[rp][ct] = __builtin_amdgcn_mfma_f32_16x16x32_bf16(afrag, bfrag[ct], acc2[rp][ct], 0, 0, 0);
    }
  }
  __syncthreads();  // all waves done reading v
  // bias + tanh + write u frags over the v region.
  // value u[k_u = w*64 + rp*16 + quad*4 + reg][edge = ct*16 + col] goes to
  // granule (ct*8 + w*2 + (rp>>1))*64 + ((rp&1)*2 + (quad>>1))*16 + col,
  // ushort offset (quad&1)*4  (derivation: ks=k>>5, q=(k>>3)&3, j=k&7).
#pragma unroll
  for (int rp = 0; rp < 4; ++rp) {
    float4 bb = *(const float4*)(b2 + w * 64 + rp * 16 + quad * 4);
#pragma unroll
    for (int ct = 0; ct < 4; ++ct) {
      float u0 = fast_tanh(acc2[rp][ct][0] + bb.x);
      float u1 = fast_tanh(acc2[rp][ct][1] + bb.y);
      float u2 = fast_tanh(acc2[rp][ct][2] + bb.z);
      float u3 = fast_tanh(acc2[rp][ct][3] + bb.w);
      uint2 d;
      d.x = (uint_t)f2bf(u0) | ((uint_t)f2bf(u1) << 16);
      d.y = (uint_t)f2bf(u2) | ((uint_t)f2bf(u3) << 16);
      const int gidx = (ct * 8 + w * 2 + (rp >> 1)) * 64 + ((rp & 1) * 2 + (quad >> 1)) * 16 + col;
      *(uint2*)&vB[gidx * 8 + (quad & 1) * 4] = d;
    }
  }
  __syncthreads();  // u ready for all waves
  // stage 3: msg^T: wave w does A-rows rt3 = 2w..2w+1, all ct
  f32x4 acc3[2][4];
#pragma unroll
  for (int rp = 0; rp < 2; ++rp)
#pragma unroll
    for (int ct = 0; ct < 4; ++ct) acc3[rp][ct] = (f32x4){0.f, 0.f, 0.f, 0.f};
#pragma unroll
  for (int ks = 0; ks < 8; ++ks) {
    bf16x8 bfrag[4];
#pragma unroll
    for (int ct = 0; ct < 4; ++ct)
      bfrag[ct] = *(const bf16x8*)&vB[((ct * 8 + ks) * 64 + l) * 8];
#pragma unroll
    for (int rp = 0; rp < 2; ++rp) {
      bf16x8 afrag = *(const bf16x8*)&W3p[((size_t)((w * 2 + rp) * 8 + ks) * 64 + l) * 8];
#pragma unroll
      for (int ct = 0; ct < 4; ++ct)
        acc3[rp][ct] = __builtin_amdgcn_mfma_f32_16x16x32_bf16(afrag, bfrag[ct], acc3[rp][ct], 0, 0, 0);
    }
  }
  __syncthreads();  // all waves done reading u
  // write msg (+b3) to vBf[edge][m], stride 132: lane has m = w*32+rp*16+quad*4+reg
  {
#pragma unroll
    for (int rp = 0; rp < 2; ++rp) {
      const int m0 = w * 32 + rp * 16 + quad * 4;
      float4 b3v = *(const float4*)(b3 + m0);
#pragma unroll
      for (int ct = 0; ct < 4; ++ct) {
        float4 o4;
        o4.x = acc3[rp][ct][0] + b3v.x;
        o4.y = acc3[rp][ct][1] + b3v.y;
        o4.z = acc3[rp][ct][2] + b3v.z;
        o4.w = acc3[rp][ct][3] + b3v.w;
        *(float4*)(vBf + (ct * 16 + col) * 132 + m0) = o4;
      }
    }
  }
  __syncthreads();
  // segmented reduction with folded 1/deg: thread t owns column j = t&127 over
  // edges [hb*32,(hb+1)*32); tIdx[e] is uniform across the half-block -> no divergence
  {
    const int j = t & 127;
    const int hb = t >> 7;
    const float* colp = vBf + j;
    int cur = tIdx[hb * 32];
    float a = 0.f;
    for (int e = hb * 32; e < hb * 32 + 32; ++e) {
      int tg = tIdx[e];
      if (tg != cur) {
        if (cur >= 0) atomicAdd(&agg[(size_t)cur * DD + j], a * invc[cur]);
        a = 0.f;
        cur = tg;
      }
      a += colp[e * 132];
    }
    if (cur >= 0) atomicAdd(&agg[(size_t)cur * DD + j], a * invc[cur]);
  }
}

__global__ void gru_gate_kernel(const float* __restrict__ gi, const float* __restrict__ gh,
                                float* __restrict__ h) {
  int idx = blockIdx.x * blockDim.x + threadIdx.x;
  if (idx >= NN * DD) return;
  int n = idx >> 7, j = idx & (DD - 1);
  const float* gir = gi + (size_t)n * (3 * DD);
  const float* ghr = gh + (size_t)n * (3 * DD);
  float r = fast_sigmoid(gir[j] + ghr[j]);
  float z = fast_sigmoid(gir[DD + j] + ghr[DD + j]);
  float nv = fast_tanh(gir[2 * DD + j] + r * ghr[2 * DD + j]);
  float hv = h[idx];
  h[idx] = (1.0f - z) * nv + z * hv;
}

__global__ __launch_bounds__(256) void dec3_kernel(const float* __restrict__ o2,
                                                   const float* __restrict__ W3,
                                                   const float* __restrict__ b3,
                                                   float* __restrict__ out) {
  int lane = threadIdx.x & 63;
  int n = blockIdx.x * 4 + (threadIdx.x >> 6);
  if (n >= NN) return;
  const float* r = o2 + (size_t)n * HH;
  float p = 0.f;
#pragma unroll
  for (int i = 0; i < 4; ++i) p = fmaf(r[lane + 64 * i], W3[lane + 64 * i], p);
  for (int off = 32; off > 0; off >>= 1) p += __shfl_down(p, off);
  if (lane == 0) out[n] = p + b3[0];
}

extern "C" void kernel_launch(void* const* d_in, const int* in_sizes, int n_in,
                              void* d_out, int out_size, void* d_ws, size_t ws_size,
                              hipStream_t stream) {
  const float* x      = (const float*)d_in[0];
  const int*   ei     = (const int*)d_in[1];
  const float* enc_W  = (const float*)d_in[2];
  const float* enc_b  = (const float*)d_in[3];
  const float* msg_W1 = (const float*)d_in[4];
  const float* msg_b1 = (const float*)d_in[5];
  const float* msg_W2 = (const float*)d_in[6];
  const float* msg_b2 = (const float*)d_in[7];
  const float* msg_W3 = (const float*)d_in[8];
  const float* msg_b3 = (const float*)d_in[9];
  const float* gWih   = (const float*)d_in[10];
  const float* gWhh   = (const float*)d_in[11];
  const float* gbih   = (const float*)d_in[12];
  const float* gbhh   = (const float*)d_in[13];
  const float* dW1    = (const float*)d_in[14];
  const float* db1    = (const float*)d_in[15];
  const float* dW2    = (const float*)d_in[16];
  const float* db2    = (const float*)d_in[17];
  const float* dW3    = (const float*)d_in[18];
  const float* db3    = (const float*)d_in[19];
  float* out = (float*)d_out;

  float* ws = (float*)d_ws;
  float* invc = ws;                                   // N  (1/deg incl self loop)
  float* h    = ws + NN;                              // 128N
  float* agg  = h + (size_t)NN * DD;                  // 128N
  float* R    = agg + (size_t)NN * DD;                // 768N shared scratch
  // bf16 P arrays: NN*HH ushorts = 128N floats each
  ushort_t* Ptb = (ushort_t*)R;                       // [R, R+128N)
  ushort_t* Psb = (ushort_t*)(R + (size_t)128 * NN);  // [R+128N, R+256N)
  float* gi = R;                                      // alias (P dead by then)
  float* gh = R + (size_t)NN * 3 * DD;
  float* o1 = R;                                      // alias (gi dead by then)
  float* o2 = R + (size_t)NN * HH;
  ushort_t* W2pk = (ushort_t*)(R + (size_t)512 * NN); // 128 KiB (dead window; repacked each layer)
  ushort_t* W3pk = W2pk + (size_t)HH * HH;            // 64 KiB
  // CSR sort arrays beyond the R region (+7.2 MB): persist across all layers
  int* deg    = (int*)(R + (size_t)768 * NN);         // N
  int* cursor = deg + NN;                             // N
  int* sSrc   = cursor + NN;                          // ET
  int* sTgt   = sSrc + ET;                            // ET

  const int* esrc = ei;        // edge_index[0] = x_j source
  const int* etgt = ei + NE;   // edge_index[1] = aggregation bucket

  // ---- build target-sorted edge list (once; reused 3 layers) ----
  hipMemsetAsync(deg, 0, NN * sizeof(int), stream);
  deg_kernel<<<(ET + 255) / 256, 256, 0, stream>>>(etgt, deg);
  scan_kernel<<<1, 1024, 0, stream>>>(deg, cursor, invc);
  scatter_kernel<<<(ET + 255) / 256, 256, 0, stream>>>(esrc, etgt, cursor, sSrc, sTgt);

  encoder_kernel<<<(NN * DD + 255) / 256, 256, 0, stream>>>(x, enc_W, enc_b, h);

  dim3 gP((NN + 63) / 64, 2);   // NO=256
  dim3 gG((NN + 63) / 64, 3);   // NO=384
  for (int l = 0; l < NLAYERS; ++l) {
    const float* W1 = msg_W1 + (size_t)l * 2 * DD * HH;
    gemm_kernel<DD, false, true><<<gP, 256, 0, stream>>>(h, W1, msg_b1 + l * HH, Ptb, NN, HH);
    gemm_kernel<DD, false, true><<<gP, 256, 0, stream>>>(h, W1 + (size_t)DD * HH, nullptr, Psb, NN, HH);
    pack_weight_kernel<<<(16 * 8 * 64 + 255) / 256, 256, 0, stream>>>(
        msg_W2 + (size_t)l * HH * HH, W2pk, HH, 16 * 8);
    pack_weight_kernel<<<(8 * 8 * 64 + 255) / 256, 256, 0, stream>>>(
        msg_W3 + (size_t)l * HH * DD, W3pk, DD, 8 * 8);
    hipMemsetAsync(agg, 0, (size_t)NN * DD * sizeof(float), stream);
    edge_kernel<<<(ET + 63) / 64, 256, 0, stream>>>(
        sSrc, sTgt, Ptb, Psb, W2pk, msg_b2 + (size_t)l * HH,
        W3pk, msg_b3 + (size_t)l * DD, invc, agg);
    gemm_kernel<DD, false, false><<<gG, 256, 0, stream>>>(
        agg, gWih + (size_t)l * DD * 3 * DD, gbih + (size_t)l * 3 * DD, gi, NN, 3 * DD);
    gemm_kernel<DD, false, false><<<gG, 256, 0, stream>>>(
        h, gWhh + (size_t)l * DD * 3 * DD, gbhh + (size_t)l * 3 * DD, gh, NN, 3 * DD);
    gru_gate_kernel<<<(NN * DD + 255) / 256, 256, 0, stream>>>(gi, gh, h);
  }
  gemm_kernel<DD, true, false><<<gP, 256, 0, stream>>>(h, dW1, db1, o1, NN, HH);
  gemm_kernel<HH, true, false><<<gP, 256, 0, stream>>>(o1, dW2, db2, o2, NN, HH);
  dec3_kernel<<<NN / 4, 256, 0, stream>>>(o2, dW3, db3, out);
}

// Round 6
// 1574.509 us; speedup vs baseline: 6.3306x; 1.5952x over previous
//
#include <hip/hip_runtime.h>
#include <math.h>

#define NN 50000
#define NP 50048      // NN padded to 64; all node arrays sized NP
#define NB 782        // NP/64
#define IN_DIM 16
#define DD 128
#define HH 256
#define NE 800000
#define NLAYERS 3
#define ET (NE + NN)

typedef unsigned short ushort_t;
typedef unsigned int uint_t;
typedef __attribute__((ext_vector_type(8))) short bf16x8;   // 8 bf16 = 4 VGPRs
typedef __attribute__((ext_vector_type(4))) float f32x4;

// tanh(x) = 1 - 2*rcp(exp2(2x*log2e)+1); ±inf exact
__device__ __forceinline__ float fast_tanh(float x) {
  float e = __builtin_amdgcn_exp2f(x * 2.88539008177793f);
  float r = __builtin_amdgcn_rcpf(e + 1.0f);
  return fmaf(-2.0f, r, 1.0f);
}

__device__ __forceinline__ float fast_sigmoid(float x) {
  float e = __builtin_amdgcn_exp2f(x * -1.44269504088896f);
  return __builtin_amdgcn_rcpf(e + 1.0f);
}

__device__ __forceinline__ ushort_t f2bf(float f) {  // RNE fp32->bf16
  uint_t u = __float_as_uint(f);
  u += 0x7FFFu + ((u >> 16) & 1u);
  return (ushort_t)(u >> 16);
}

__device__ __forceinline__ float bflo(uint_t d) { return __uint_as_float(d << 16); }
__device__ __forceinline__ float bfhi(uint_t d) { return __uint_as_float(d & 0xFFFF0000u); }

// h_bf / agg-frag GLOBAL layout (B-operand frags, K=128), per 64-node group:
//   addr = g64*8192 + ((ct*4 + ks)*64 + q*16 + mr)*8 + j
//   where node = g64*64 + ct*16 + mr, k = ks*32 + q*8 + j.
// Consumer: lane l reads bf16x8 at ((ct*4+ks)*64 + l)*8  ->  B[k=(l>>4)*8+j][n=l&15].

// ---------------- CSR counting sort (built once, reused 3 layers) ----------------

__global__ void deg_kernel(const int* __restrict__ etgt, int* __restrict__ deg) {
  int e = blockIdx.x * blockDim.x + threadIdx.x;
  if (e >= ET) return;
  int tg = (e < NE) ? etgt[e] : (e - NE);
  atomicAdd(&deg[tg], 1);
}

__global__ __launch_bounds__(1024) void scan_kernel(const int* __restrict__ deg,
                                                    int* __restrict__ cursor,
                                                    float* __restrict__ invc) {
  __shared__ int wsum[16];
  __shared__ int carry_s;
  const int t = threadIdx.x;
  const int lane = t & 63, wid = t >> 6;
  if (t == 0) carry_s = 0;
  __syncthreads();
  for (int base = 0; base < NN; base += 1024) {
    int i = base + t;
    int d = (i < NN) ? deg[i] : 0;
    int v = d;
#pragma unroll
    for (int off = 1; off < 64; off <<= 1) {
      int u = __shfl_up(v, off);
      if (lane >= off) v += u;
    }
    if (lane == 63) wsum[wid] = v;
    __syncthreads();
    int woff = 0;
    for (int k = 0; k < wid; ++k) woff += wsum[k];
    int incl = v + woff;
    int carry = carry_s;
    __syncthreads();
    if (i < NN) {
      cursor[i] = carry + incl - d;
      invc[i] = 1.0f / (float)d;
    }
    if (t == 1023) carry_s = carry + incl;
    __syncthreads();
  }
}

__global__ void scatter_kernel(const int* __restrict__ esrc, const int* __restrict__ etgt,
                               int* __restrict__ cursor, int* __restrict__ sSrc,
                               int* __restrict__ sTgt) {
  int e = blockIdx.x * blockDim.x + threadIdx.x;
  if (e >= ET) return;
  int s, tg;
  if (e < NE) { s = esrc[e]; tg = etgt[e]; }
  else        { s = e - NE;  tg = s; }
  int pos = atomicAdd(&cursor[tg], 1);
  sSrc[pos] = s;
  sTgt[pos] = tg;
}

// ---------------------------------------------------------------------------------

__global__ void encoder_kernel(const float* __restrict__ x, const float* __restrict__ W,
                               const float* __restrict__ b, float* __restrict__ h,
                               ushort_t* __restrict__ hbf) {
  int idx = blockIdx.x * blockDim.x + threadIdx.x;
  if (idx >= NN * DD) return;
  int n = idx >> 7, j = idx & (DD - 1);
  const float* xr = x + n * IN_DIM;
  float acc = b[j];
#pragma unroll
  for (int k = 0; k < IN_DIM; ++k) acc = fmaf(xr[k], W[k * DD + j], acc);
  float v = fast_tanh(acc);
  h[idx] = v;
  const int ct = (n >> 4) & 3, mr = n & 15, ks = j >> 5, q = (j >> 3) & 3, jj = j & 7;
  hbf[(size_t)(n >> 6) * 8192 + (((ct * 4 + ks) * 64) + q * 16 + mr) * 8 + jj] = f2bf(v);
}

// Pack W[K x M] (row-major) into bf16 A-frag order for out^T = W^T @ act^T:
//   out[((rt*kb + ks)*64 + lane)*8 + j] = bf16(W[(ks*32 + (lane>>4)*8 + j)*M + rt*16 + (lane&15)])
// blockIdx.y = layer.
__global__ void pack_kernel(const float* __restrict__ W, ushort_t* __restrict__ out,
                            int M, int kbsh, int ngrp, int srcStride, int outStride) {
  int tid = blockIdx.x * blockDim.x + threadIdx.x;
  if (tid >= ngrp * 64) return;
  const float* Ws = W + (size_t)blockIdx.y * srcStride;
  ushort_t* os = out + (size_t)blockIdx.y * outStride;
  int lane = tid & 63, g = tid >> 6;
  int ks = g & ((1 << kbsh) - 1);
  int rt = g >> kbsh;
  int m = rt * 16 + (lane & 15);
  int k0 = ks * 32 + ((lane >> 4) << 3);
  uint_t p[4];
#pragma unroll
  for (int d = 0; d < 4; ++d) {
    ushort_t lo = f2bf(Ws[(size_t)(k0 + 2 * d) * M + m]);
    ushort_t hi = f2bf(Ws[(size_t)(k0 + 2 * d + 1) * M + m]);
    p[d] = (uint_t)lo | ((uint_t)hi << 16);
  }
  uint4 o;
  o.x = p[0]; o.y = p[1]; o.z = p[2]; o.w = p[3];
  *(uint4*)(os + (size_t)tid * 8) = o;
}

// Pt/Ps = h @ W1 (+b1 on Pt), MFMA, no LDS. 64 nodes/block, 4 waves.
// W1pk packed kb=8 (rows 0-127 = Pt half -> ks 0-3; rows 128-255 = Ps -> ks 4-7).
__global__ __launch_bounds__(256) void proj_kernel(
    const ushort_t* __restrict__ hbf, const ushort_t* __restrict__ W1p,
    const float* __restrict__ b1, ushort_t* __restrict__ Ptb, ushort_t* __restrict__ Psb) {
  const int t = threadIdx.x, blk = blockIdx.x;
  const int w = t >> 6, l = t & 63, quad = l >> 4, col = l & 15;
  const ushort_t* hb = hbf + (size_t)blk * 8192;
#pragma unroll
  for (int half = 0; half < 2; ++half) {
    f32x4 acc[4][4];
#pragma unroll
    for (int m = 0; m < 4; ++m)
#pragma unroll
      for (int ct = 0; ct < 4; ++ct) acc[m][ct] = (f32x4){0.f, 0.f, 0.f, 0.f};
#pragma unroll
    for (int ks = 0; ks < 4; ++ks) {
      bf16x8 af[4];
#pragma unroll
      for (int m = 0; m < 4; ++m)
        af[m] = *(const bf16x8*)&W1p[((size_t)((w * 4 + m) * 8 + half * 4 + ks) * 64 + l) * 8];
#pragma unroll
      for (int ct = 0; ct < 4; ++ct) {
        bf16x8 bf = *(const bf16x8*)&hb[((ct * 4 + ks) * 64 + l) * 8];
#pragma unroll
        for (int m = 0; m < 4; ++m)
          acc[m][ct] = __builtin_amdgcn_mfma_f32_16x16x32_bf16(af[m], bf, acc[m][ct], 0, 0, 0);
      }
    }
    ushort_t* out = half ? Psb : Ptb;
#pragma unroll
    for (int m = 0; m < 4; ++m) {
      const int o0 = (w * 4 + m) * 16 + quad * 4;
      f32x4 bb = (f32x4){0.f, 0.f, 0.f, 0.f};
      if (half == 0) bb = *(const f32x4*)(b1 + o0);
#pragma unroll
      for (int ct = 0; ct < 4; ++ct) {
        const size_t node = (size_t)blk * 64 + ct * 16 + col;
        uint2 d;
        d.x = (uint_t)f2bf(acc[m][ct][0] + bb[0]) | ((uint_t)f2bf(acc[m][ct][1] + bb[1]) << 16);
        d.y = (uint_t)f2bf(acc[m][ct][2] + bb[2]) | ((uint_t)f2bf(acc[m][ct][3] + bb[3]) << 16);
        *(uint2*)&out[node * HH + o0] = d;
      }
    }
  }
}

// MFMA edge kernel (unchanged from R5 — verified).
__global__ __launch_bounds__(256, 3) void edge_kernel(
    const int* __restrict__ sSrc, const int* __restrict__ sTgt,
    const ushort_t* __restrict__ Ptb, const ushort_t* __restrict__ Psb,
    const ushort_t* __restrict__ W2p, const float* __restrict__ b2,
    const ushort_t* __restrict__ W3p, const float* __restrict__ b3,
    const float* __restrict__ invc, float* __restrict__ agg) {
  __shared__ __align__(16) float vBf[64 * 132];
  __shared__ int sIdx[64];
  __shared__ int tIdx[64];
  ushort_t* vB = (ushort_t*)vBf;
  const int t = threadIdx.x;
  const int e0 = blockIdx.x * 64;
  if (t < 64) {
    int e = e0 + t;
    int s = 0, tg = -1;
    if (e < ET) { s = sSrc[e]; tg = sTgt[e]; }
    sIdx[t] = s;
    tIdx[t] = tg;
  }
  __syncthreads();
  {
    const int el = t & 63, c = t >> 6;
    int tg = tIdx[el]; if (tg < 0) tg = 0;
    const int s = sIdx[el];
    const uint4* pt = (const uint4*)(Ptb + (size_t)tg * HH + c * 64);
    const uint4* ps = (const uint4*)(Psb + (size_t)s * HH + c * 64);
    const int ct = el >> 4, mr = el & 15;
#pragma unroll
    for (int g = 0; g < 8; ++g) {
      uint4 av = pt[g];
      uint4 bv = ps[g];
      uint_t ad[4] = {av.x, av.y, av.z, av.w};
      uint_t bd[4] = {bv.x, bv.y, bv.z, bv.w};
      uint_t p[4];
#pragma unroll
      for (int d = 0; d < 4; ++d) {
        float flo = bflo(ad[d]) + bflo(bd[d]);
        float fhi = bfhi(ad[d]) + bfhi(bd[d]);
        ushort_t lo = f2bf(fast_tanh(flo));
        ushort_t hi = f2bf(fast_tanh(fhi));
        p[d] = (uint_t)lo | ((uint_t)hi << 16);
      }
      uint4 o;
      o.x = p[0]; o.y = p[1]; o.z = p[2]; o.w = p[3];
      const int ks = c * 2 + (g >> 2);
      const int quad = g & 3;
      *(uint4*)&vB[((ct * 8 + ks) * 64 + quad * 16 + mr) * 8] = o;
    }
  }
  __syncthreads();
  const int w = t >> 6, l = t & 63;
  const int quad = l >> 4, col = l & 15;
  f32x4 acc2[4][4];
#pragma unroll
  for (int rp = 0; rp < 4; ++rp)
#pragma unroll
    for (int ct = 0; ct < 4; ++ct) acc2[rp][ct] = (f32x4){0.f, 0.f, 0.f, 0.f};
#pragma unroll
  for (int ks = 0; ks < 8; ++ks) {
    bf16x8 bfrag[4];
#pragma unroll
    for (int ct = 0; ct < 4; ++ct)
      bfrag[ct] = *(const bf16x8*)&vB[((ct * 8 + ks) * 64 + l) * 8];
#pragma unroll
    for (int rp = 0; rp < 4; ++rp) {
      bf16x8 afrag = *(const bf16x8*)&W2p[((size_t)((w * 4 + rp) * 8 + ks) * 64 + l) * 8];
#pragma unroll
      for (int ct = 0; ct < 4; ++ct)
        acc2[rp][ct] = __builtin_amdgcn_mfma_f32_16x16x32_bf16(afrag, bfrag[ct], acc2[rp][ct], 0, 0, 0);
    }
  }
  __syncthreads();
#pragma unroll
  for (int rp = 0; rp < 4; ++rp) {
    f32x4 bb = *(const f32x4*)(b2 + w * 64 + rp * 16 + quad * 4);
#pragma unroll
    for (int ct = 0; ct < 4; ++ct) {
      float u0 = fast_tanh(acc2[rp][ct][0] + bb[0]);
      float u1 = fast_tanh(acc2[rp][ct][1] + bb[1]);
      float u2 = fast_tanh(acc2[rp][ct][2] + bb[2]);
      float u3 = fast_tanh(acc2[rp][ct][3] + bb[3]);
      uint2 d;
      d.x = (uint_t)f2bf(u0) | ((uint_t)f2bf(u1) << 16);
      d.y = (uint_t)f2bf(u2) | ((uint_t)f2bf(u3) << 16);
      const int gidx = (ct * 8 + w * 2 + (rp >> 1)) * 64 + ((rp & 1) * 2 + (quad >> 1)) * 16 + col;
      *(uint2*)&vB[gidx * 8 + (quad & 1) * 4] = d;
    }
  }
  __syncthreads();
  f32x4 acc3[2][4];
#pragma unroll
  for (int rp = 0; rp < 2; ++rp)
#pragma unroll
    for (int ct = 0; ct < 4; ++ct) acc3[rp][ct] = (f32x4){0.f, 0.f, 0.f, 0.f};
#pragma unroll
  for (int ks = 0; ks < 8; ++ks) {
    bf16x8 bfrag[4];
#pragma unroll
    for (int ct = 0; ct < 4; ++ct)
      bfrag[ct] = *(const bf16x8*)&vB[((ct * 8 + ks) * 64 + l) * 8];
#pragma unroll
    for (int rp = 0; rp < 2; ++rp) {
      bf16x8 afrag = *(const bf16x8*)&W3p[((size_t)((w * 2 + rp) * 8 + ks) * 64 + l) * 8];
#pragma unroll
      for (int ct = 0; ct < 4; ++ct)
        acc3[rp][ct] = __builtin_amdgcn_mfma_f32_16x16x32_bf16(afrag, bfrag[ct], acc3[rp][ct], 0, 0, 0);
    }
  }
  __syncthreads();
  {
#pragma unroll
    for (int rp = 0; rp < 2; ++rp) {
      const int m0 = w * 32 + rp * 16 + quad * 4;
      f32x4 b3v = *(const f32x4*)(b3 + m0);
#pragma unroll
      for (int ct = 0; ct < 4; ++ct) {
        float4 o4;
        o4.x = acc3[rp][ct][0] + b3v[0];
        o4.y = acc3[rp][ct][1] + b3v[1];
        o4.z = acc3[rp][ct][2] + b3v[2];
        o4.w = acc3[rp][ct][3] + b3v[3];
        *(float4*)(vBf + (ct * 16 + col) * 132 + m0) = o4;
      }
    }
  }
  __syncthreads();
  {
    const int j = t & 127;
    const int hb = t >> 7;
    const float* colp = vBf + j;
    int cur = tIdx[hb * 32];
    float a = 0.f;
    for (int e = hb * 32; e < hb * 32 + 32; ++e) {
      int tg = tIdx[e];
      if (tg != cur) {
        if (cur >= 0) atomicAdd(&agg[(size_t)cur * DD + j], a * invc[cur]);
        a = 0.f;
        cur = tg;
      }
      a += colp[e * 132];
    }
    if (cur >= 0) atomicAdd(&agg[(size_t)cur * DD + j], a * invc[cur]);
  }
}

// Fused GRU: gate = [agg | h] @ [Wih ; Whh] via K=256 MFMA (n-gate gi/gh split),
// gates in-register, writes h fp32 (via LDS, coalesced) + h_bf frags (double-buffered).
// Wave w owns output row-tiles rt = w + 4i, i<6 (r: i=0,1; z: i=2,3; n: i=4,5).
__global__ __launch_bounds__(256, 2) void gru_kernel(
    const float* __restrict__ agg, const float* __restrict__ hg,
    const ushort_t* __restrict__ hbf_in,
    const ushort_t* __restrict__ Wihp, const ushort_t* __restrict__ Whhp,
    const float* __restrict__ bih, const float* __restrict__ bhh,
    float* __restrict__ hg_out, ushort_t* __restrict__ hbf_out) {
  __shared__ __align__(16) ushort_t aggF[64 * 128];  // 16 KB, B-frag
  __shared__ __align__(16) float hT[64 * 132];       // 33.8 KB
  const int t = threadIdx.x, blk = blockIdx.x;
  const size_t nodeBase = (size_t)blk * 64;
  // phase 1: stage agg -> frags, h -> fp32 tile (both coalesced)
  {
    const int row = t >> 2, c = t & 3;  // c = ks (32 k each)
    const float4* ap = (const float4*)(agg + (nodeBase + row) * DD + c * 32);
    const int ct = row >> 4, mr = row & 15;
#pragma unroll
    for (int g = 0; g < 8; ++g) {  // k = c*32 + g*4 + r : q = g>>1, j = (g&1)*4 + r
      float4 v = ap[g];
      uint2 d;
      d.x = (uint_t)f2bf(v.x) | ((uint_t)f2bf(v.y) << 16);
      d.y = (uint_t)f2bf(v.z) | ((uint_t)f2bf(v.w) << 16);
      *(uint2*)&aggF[(((ct * 4 + c) * 64) + (g >> 1) * 16 + mr) * 8 + (g & 1) * 4] = d;
    }
    const float4* hp = (const float4*)(hg + (nodeBase + row) * DD + c * 32);
    float* hrow = hT + row * 132 + c * 32;
#pragma unroll
    for (int g = 0; g < 8; ++g) *(float4*)(hrow + g * 4) = hp[g];
  }
  __syncthreads();
  const int w = t >> 6, l = t & 63, quad = l >> 4, col = l & 15;
  const ushort_t* hbf_blk = hbf_in + nodeBase * DD;
  // biases (per output-dim slice, ct-independent)
  f32x4 bbr[2], bbz[2], bbin[2], bbhn[2];
#pragma unroll
  for (int m = 0; m < 2; ++m) {
    const int o = (w + 4 * m) * 16 + quad * 4;
    f32x4 i0 = *(const f32x4*)(bih + o),       h0 = *(const f32x4*)(bhh + o);
    f32x4 i1 = *(const f32x4*)(bih + o + 128), h1 = *(const f32x4*)(bhh + o + 128);
    bbr[m] = i0 + h0;
    bbz[m] = i1 + h1;
    bbin[m] = *(const f32x4*)(bih + o + 256);
    bbhn[m] = *(const f32x4*)(bhh + o + 256);
  }
  for (int ct = 0; ct < 4; ++ct) {
    f32x4 acc[8];
#pragma unroll
    for (int i = 0; i < 8; ++i) acc[i] = (f32x4){0.f, 0.f, 0.f, 0.f};
#pragma unroll
    for (int ks = 0; ks < 8; ++ks) {
      bf16x8 bfrag;
      if (ks < 4) bfrag = *(const bf16x8*)&aggF[((ct * 4 + ks) * 64 + l) * 8];
      else        bfrag = *(const bf16x8*)&hbf_blk[((ct * 4 + (ks - 4)) * 64 + l) * 8];
#pragma unroll
      for (int i = 0; i < 6; ++i) {
        const int rt = w + 4 * i;
        bf16x8 afrag = (ks < 4)
            ? *(const bf16x8*)&Wihp[((size_t)(rt * 4 + ks) * 64 + l) * 8]
            : *(const bf16x8*)&Whhp[((size_t)(rt * 4 + ks - 4) * 64 + l) * 8];
        const int tgt = (i < 4) ? i : ((ks < 4) ? i : i + 2);
        acc[tgt] = __builtin_amdgcn_mfma_f32_16x16x32_bf16(afrag, bfrag, acc[tgt], 0, 0, 0);
      }
    }
    // gates + writeback
#pragma unroll
    for (int m = 0; m < 2; ++m) {
      const int or0 = (w + 4 * m) * 16 + quad * 4;
      float* hrow = hT + (ct * 16 + col) * 132 + or0;
      f32x4 hv = *(const f32x4*)hrow;
      f32x4 hnew;
      ushort_t hb[4];
#pragma unroll
      for (int r = 0; r < 4; ++r) {
        float rr = fast_sigmoid(acc[m][r] + bbr[m][r]);
        float zz = fast_sigmoid(acc[2 + m][r] + bbz[m][r]);
        float gin = acc[4 + m][r] + bbin[m][r];
        float ghn = acc[6 + m][r] + bbhn[m][r];
        float nn = fast_tanh(fmaf(rr, ghn, gin));
        float hn = fmaf(zz, hv[r] - nn, nn);
        hnew[r] = hn;
        hb[r] = f2bf(hn);
      }
      *(f32x4*)hrow = hnew;
      uint2 d;
      d.x = (uint_t)hb[0] | ((uint_t)hb[1] << 16);
      d.y = (uint_t)hb[2] | ((uint_t)hb[3] << 16);
      const int ksn = 2 * m + (w >> 1);
      const int qn = 2 * (w & 1) + (quad >> 1);
      *(uint2*)&hbf_out[nodeBase * DD + (((ct * 4 + ksn) * 64) + qn * 16 + col) * 8 + 4 * (quad & 1)] = d;
    }
  }
  __syncthreads();
  // phase 3: coalesced hT -> h global
  {
    const int row = t >> 2, c = t & 3;
    float* dst = hg_out + (nodeBase + row) * DD + c * 32;
    const float* src = hT + row * 132 + c * 32;
#pragma unroll
    for (int g = 0; g < 8; ++g) *(float4*)(dst + g * 4) = *(const float4*)(src + g * 4);
  }
}

// Fused decoder: o1 = tanh(h@dW1+b1) -> LDS frags; o2 = tanh(o1@dW2+b2) folded
// directly into dot with dW3 (never materialized); LDS cross-wave reduce.
__global__ __launch_bounds__(256) void dec_kernel(
    const ushort_t* __restrict__ hbf, const ushort_t* __restrict__ W1p,
    const float* __restrict__ b1, const ushort_t* __restrict__ W2p,
    const float* __restrict__ b2, const float* __restrict__ w3,
    const float* __restrict__ b3, float* __restrict__ out) {
  __shared__ __align__(16) ushort_t o1F[64 * 256];  // 32 KB
  __shared__ float red[16][64];                     // 4 KB
  const int t = threadIdx.x, blk = blockIdx.x;
  const int w = t >> 6, l = t & 63, quad = l >> 4, col = l & 15;
  const ushort_t* hb = hbf + (size_t)blk * 8192;
  // phase 1
  {
    f32x4 a1[4][4];
#pragma unroll
    for (int m = 0; m < 4; ++m)
#pragma unroll
      for (int ct = 0; ct < 4; ++ct) a1[m][ct] = (f32x4){0.f, 0.f, 0.f, 0.f};
#pragma unroll
    for (int ks = 0; ks < 4; ++ks) {
      bf16x8 af[4];
#pragma unroll
      for (int m = 0; m < 4; ++m)
        af[m] = *(const bf16x8*)&W1p[((size_t)((w * 4 + m) * 4 + ks) * 64 + l) * 8];
#pragma unroll
      for (int ct = 0; ct < 4; ++ct) {
        bf16x8 bf = *(const bf16x8*)&hb[((ct * 4 + ks) * 64 + l) * 8];
#pragma unroll
        for (int m = 0; m < 4; ++m)
          a1[m][ct] = __builtin_amdgcn_mfma_f32_16x16x32_bf16(af[m], bf, a1[m][ct], 0, 0, 0);
      }
    }
#pragma unroll
    for (int m = 0; m < 4; ++m) {
      const int o0 = (w * 4 + m) * 16 + quad * 4;
      f32x4 bb = *(const f32x4*)(b1 + o0);
      const int ks1 = 2 * w + (m >> 1);
      const int q1 = 2 * (m & 1) + (quad >> 1);
#pragma unroll
      for (int ct = 0; ct < 4; ++ct) {
        uint2 d;
        d.x = (uint_t)f2bf(fast_tanh(a1[m][ct][0] + bb[0])) |
              ((uint_t)f2bf(fast_tanh(a1[m][ct][1] + bb[1])) << 16);
        d.y = (uint_t)f2bf(fast_tanh(a1[m][ct][2] + bb[2])) |
              ((uint_t)f2bf(fast_tanh(a1[m][ct][3] + bb[3])) << 16);
        *(uint2*)&o1F[((ct * 8 + ks1) * 64 + q1 * 16 + col) * 8 + 4 * (quad & 1)] = d;
      }
    }
  }
  __syncthreads();
  // phase 2
  {
    f32x4 a2[4][4];
#pragma unroll
    for (int m = 0; m < 4; ++m)
#pragma unroll
      for (int ct = 0; ct < 4; ++ct) a2[m][ct] = (f32x4){0.f, 0.f, 0.f, 0.f};
#pragma unroll
    for (int ks = 0; ks < 8; ++ks) {
      bf16x8 af[4];
#pragma unroll
      for (int m = 0; m < 4; ++m)
        af[m] = *(const bf16x8*)&W2p[((size_t)((w * 4 + m) * 8 + ks) * 64 + l) * 8];
#pragma unroll
      for (int ct = 0; ct < 4; ++ct) {
        bf16x8 bf = *(const bf16x8*)&o1F[((ct * 8 + ks) * 64 + l) * 8];
#pragma unroll
        for (int m = 0; m < 4; ++m)
          a2[m][ct] = __builtin_amdgcn_mfma_f32_16x16x32_bf16(af[m], bf, a2[m][ct], 0, 0, 0);
      }
    }
    float partial[4] = {0.f, 0.f, 0.f, 0.f};
#pragma unroll
    for (int m = 0; m < 4; ++m) {
      const int o0 = (w * 4 + m) * 16 + quad * 4;
      f32x4 b2v = *(const f32x4*)(b2 + o0);
      f32x4 w3v = *(const f32x4*)(w3 + o0);
#pragma unroll
      for (int ct = 0; ct < 4; ++ct)
#pragma unroll
        for (int r = 0; r < 4; ++r)
          partial[ct] += fast_tanh(a2[m][ct][r] + b2v[r]) * w3v[r];
    }
#pragma unroll
    for (int ct = 0; ct < 4; ++ct) red[w * 4 + quad][ct * 16 + col] = partial[ct];
  }
  __syncthreads();
  if (t < 64) {
    float s = b3[0];
#pragma unroll
    for (int k = 0; k < 16; ++k) s += red[k][t];
    size_t node = (size_t)blk * 64 + t;
    if (node < NN) out[node] = s;
  }
}

extern "C" void kernel_launch(void* const* d_in, const int* in_sizes, int n_in,
                              void* d_out, int out_size, void* d_ws, size_t ws_size,
                              hipStream_t stream) {
  const float* x      = (const float*)d_in[0];
  const int*   ei     = (const int*)d_in[1];
  const float* enc_W  = (const float*)d_in[2];
  const float* enc_b  = (const float*)d_in[3];
  const float* msg_W1 = (const float*)d_in[4];
  const float* msg_b1 = (const float*)d_in[5];
  const float* msg_W2 = (const float*)d_in[6];
  const float* msg_b2 = (const float*)d_in[7];
  const float* msg_W3 = (const float*)d_in[8];
  const float* msg_b3 = (const float*)d_in[9];
  const float* gWih   = (const float*)d_in[10];
  const float* gWhh   = (const float*)d_in[11];
  const float* gbih   = (const float*)d_in[12];
  const float* gbhh   = (const float*)d_in[13];
  const float* dW1    = (const float*)d_in[14];
  const float* db1    = (const float*)d_in[15];
  const float* dW2    = (const float*)d_in[16];
  const float* db2    = (const float*)d_in[17];
  const float* dW3    = (const float*)d_in[18];
  const float* db3    = (const float*)d_in[19];
  float* out = (float*)d_out;

  float* ws = (float*)d_ws;
  float* invc = ws;                                    // NP
  float* h    = ws + NP;                               // NP*128 fp32
  float* agg  = h + (size_t)NP * DD;                   // NP*128 fp32
  ushort_t* hbfA = (ushort_t*)(agg + (size_t)NP * DD); // NP*128 ush
  ushort_t* hbfB = hbfA + (size_t)NP * DD;             // NP*128 ush
  ushort_t* Ptb  = hbfB + (size_t)NP * DD;             // NP*256 ush
  ushort_t* Psb  = Ptb + (size_t)NP * HH;              // NP*256 ush
  ushort_t* W2pk = Psb + (size_t)NP * HH;              // 3*65536
  ushort_t* W3pk = W2pk + 3 * 65536;                   // 3*32768
  ushort_t* W1pk = W3pk + 3 * 32768;                   // 3*65536
  ushort_t* Wihpk = W1pk + 3 * 65536;                  // 3*49152
  ushort_t* Whhpk = Wihpk + 3 * 49152;                 // 3*49152
  ushort_t* dW1pk = Whhpk + 3 * 49152;                 // 32768
  ushort_t* dW2pk = dW1pk + 32768;                     // 65536
  int* deg    = (int*)(dW2pk + 65536);                 // NP
  int* cursor = deg + NP;                              // NP
  int* sSrc   = cursor + NP;                           // ET
  int* sTgt   = sSrc + ET;                             // ET

  const int* esrc = ei;
  const int* etgt = ei + NE;

  // edge sort (once)
  hipMemsetAsync(deg, 0, NN * sizeof(int), stream);
  deg_kernel<<<(ET + 255) / 256, 256, 0, stream>>>(etgt, deg);
  scan_kernel<<<1, 1024, 0, stream>>>(deg, cursor, invc);
  scatter_kernel<<<(ET + 255) / 256, 256, 0, stream>>>(esrc, etgt, cursor, sSrc, sTgt);

  encoder_kernel<<<(NN * DD + 255) / 256, 256, 0, stream>>>(x, enc_W, enc_b, h, hbfA);

  // weight packs (once, all layers)
  pack_kernel<<<dim3(32, 3), 256, 0, stream>>>(msg_W2, W2pk, 256, 3, 128, 65536, 65536);
  pack_kernel<<<dim3(16, 3), 256, 0, stream>>>(msg_W3, W3pk, 128, 3, 64, 32768, 32768);
  pack_kernel<<<dim3(32, 3), 256, 0, stream>>>(msg_W1, W1pk, 256, 3, 128, 65536, 65536);
  pack_kernel<<<dim3(24, 3), 256, 0, stream>>>(gWih, Wihpk, 384, 2, 96, 49152, 49152);
  pack_kernel<<<dim3(24, 3), 256, 0, stream>>>(gWhh, Whhpk, 384, 2, 96, 49152, 49152);
  pack_kernel<<<dim3(16, 1), 256, 0, stream>>>(dW1, dW1pk, 256, 2, 64, 0, 0);
  pack_kernel<<<dim3(32, 1), 256, 0, stream>>>(dW2, dW2pk, 256, 3, 128, 0, 0);

  for (int l = 0; l < NLAYERS; ++l) {
    const ushort_t* hin = (l & 1) ? hbfB : hbfA;
    ushort_t* hout = (l & 1) ? hbfA : hbfB;
    proj_kernel<<<NB, 256, 0, stream>>>(hin, W1pk + (size_t)l * 65536, msg_b1 + l * HH, Ptb, Psb);
    hipMemsetAsync(agg, 0, (size_t)NP * DD * sizeof(float), stream);
    edge_kernel<<<(ET + 63) / 64, 256, 0, stream>>>(
        sSrc, sTgt, Ptb, Psb, W2pk + (size_t)l * 65536, msg_b2 + (size_t)l * HH,
        W3pk + (size_t)l * 32768, msg_b3 + (size_t)l * DD, invc, agg);
    gru_kernel<<<NB, 256, 0, stream>>>(
        agg, h, hin, Wihpk + (size_t)l * 49152, Whhpk + (size_t)l * 49152,
        gbih + (size_t)l * 3 * DD, gbhh + (size_t)l * 3 * DD, h, hout);
  }
  dec_kernel<<<NB, 256, 0, stream>>>(hbfB, dW1pk, db1, dW2pk, db2, dW3, db3, out);
}

// Round 7
// 1415.180 us; speedup vs baseline: 7.0434x; 1.1126x over previous
//
#include <hip/hip_runtime.h>
#include <math.h>

#define NN 50000
#define NP 50048      // NN padded to 64; all node arrays sized NP
#define NB 782        // NP/64
#define IN_DIM 16
#define DD 128
#define HH 256
#define NE 800000
#define NLAYERS 3
#define ET (NE + NN)

typedef unsigned short ushort_t;
typedef unsigned int uint_t;
typedef __attribute__((ext_vector_type(8))) short bf16x8;   // 8 bf16 = 4 VGPRs
typedef __attribute__((ext_vector_type(4))) float f32x4;

// tanh(x) = 1 - 2*rcp(exp2(2x*log2e)+1); ±inf exact
__device__ __forceinline__ float fast_tanh(float x) {
  float e = __builtin_amdgcn_exp2f(x * 2.88539008177793f);
  float r = __builtin_amdgcn_rcpf(e + 1.0f);
  return fmaf(-2.0f, r, 1.0f);
}

__device__ __forceinline__ float fast_sigmoid(float x) {
  float e = __builtin_amdgcn_exp2f(x * -1.44269504088896f);
  return __builtin_amdgcn_rcpf(e + 1.0f);
}

__device__ __forceinline__ ushort_t f2bf(float f) {  // RNE fp32->bf16
  uint_t u = __float_as_uint(f);
  u += 0x7FFFu + ((u >> 16) & 1u);
  return (ushort_t)(u >> 16);
}

// pack 2 fp32 -> 2 bf16 (RNE) in one dword; single v_cvt_pk_bf16_f32 on gfx950
__device__ __forceinline__ uint_t pack2bf(float lo, float hi) {
#if __has_builtin(__builtin_amdgcn_cvt_pk_bf16_f32)
  auto v = __builtin_amdgcn_cvt_pk_bf16_f32(lo, hi);
  uint_t r;
  __builtin_memcpy(&r, &v, 4);
  return r;
#else
  return (uint_t)f2bf(lo) | ((uint_t)f2bf(hi) << 16);
#endif
}

__device__ __forceinline__ float bflo(uint_t d) { return __uint_as_float(d << 16); }
__device__ __forceinline__ float bfhi(uint_t d) { return __uint_as_float(d & 0xFFFF0000u); }

// h_bf / agg-frag GLOBAL layout (B-operand frags, K=128), per 64-node group:
//   addr = g64*8192 + ((ct*4 + ks)*64 + q*16 + mr)*8 + j
//   where node = g64*64 + ct*16 + mr, k = ks*32 + q*8 + j.

// ---------------- CSR counting sort (built once, reused 3 layers) ----------------

__global__ void deg_kernel(const int* __restrict__ etgt, int* __restrict__ deg) {
  int e = blockIdx.x * blockDim.x + threadIdx.x;
  if (e >= ET) return;
  int tg = (e < NE) ? etgt[e] : (e - NE);
  atomicAdd(&deg[tg], 1);
}

__global__ __launch_bounds__(1024) void scan_kernel(const int* __restrict__ deg,
                                                    int* __restrict__ cursor,
                                                    float* __restrict__ invc) {
  __shared__ int wsum[16];
  __shared__ int carry_s;
  const int t = threadIdx.x;
  const int lane = t & 63, wid = t >> 6;
  if (t == 0) carry_s = 0;
  __syncthreads();
  for (int base = 0; base < NN; base += 1024) {
    int i = base + t;
    int d = (i < NN) ? deg[i] : 0;
    int v = d;
#pragma unroll
    for (int off = 1; off < 64; off <<= 1) {
      int u = __shfl_up(v, off);
      if (lane >= off) v += u;
    }
    if (lane == 63) wsum[wid] = v;
    __syncthreads();
    int woff = 0;
    for (int k = 0; k < wid; ++k) woff += wsum[k];
    int incl = v + woff;
    int carry = carry_s;
    __syncthreads();
    if (i < NN) {
      cursor[i] = carry + incl - d;
      invc[i] = 1.0f / (float)d;
    }
    if (t == 1023) carry_s = carry + incl;
    __syncthreads();
  }
}

__global__ void scatter_kernel(const int* __restrict__ esrc, const int* __restrict__ etgt,
                               int* __restrict__ cursor, int* __restrict__ sSrc,
                               int* __restrict__ sTgt) {
  int e = blockIdx.x * blockDim.x + threadIdx.x;
  if (e >= ET) return;
  int s, tg;
  if (e < NE) { s = esrc[e]; tg = etgt[e]; }
  else        { s = e - NE;  tg = s; }
  int pos = atomicAdd(&cursor[tg], 1);
  sSrc[pos] = s;
  sTgt[pos] = tg;
}

// ---------------------------------------------------------------------------------

__global__ void encoder_kernel(const float* __restrict__ x, const float* __restrict__ W,
                               const float* __restrict__ b, float* __restrict__ h,
                               ushort_t* __restrict__ hbf) {
  int idx = blockIdx.x * blockDim.x + threadIdx.x;
  if (idx >= NN * DD) return;
  int n = idx >> 7, j = idx & (DD - 1);
  const float* xr = x + n * IN_DIM;
  float acc = b[j];
#pragma unroll
  for (int k = 0; k < IN_DIM; ++k) acc = fmaf(xr[k], W[k * DD + j], acc);
  float v = fast_tanh(acc);
  h[idx] = v;
  const int ct = (n >> 4) & 3, mr = n & 15, ks = j >> 5, q = (j >> 3) & 3, jj = j & 7;
  hbf[(size_t)(n >> 6) * 8192 + (((ct * 4 + ks) * 64) + q * 16 + mr) * 8 + jj] = f2bf(v);
}

// Pack W[K x M] (row-major) into bf16 A-frag order; blockIdx.y = layer.
__global__ void pack_kernel(const float* __restrict__ W, ushort_t* __restrict__ out,
                            int M, int kbsh, int ngrp, int srcStride, int outStride) {
  int tid = blockIdx.x * blockDim.x + threadIdx.x;
  if (tid >= ngrp * 64) return;
  const float* Ws = W + (size_t)blockIdx.y * srcStride;
  ushort_t* os = out + (size_t)blockIdx.y * outStride;
  int lane = tid & 63, g = tid >> 6;
  int ks = g & ((1 << kbsh) - 1);
  int rt = g >> kbsh;
  int m = rt * 16 + (lane & 15);
  int k0 = ks * 32 + ((lane >> 4) << 3);
  uint_t p[4];
#pragma unroll
  for (int d = 0; d < 4; ++d)
    p[d] = pack2bf(Ws[(size_t)(k0 + 2 * d) * M + m], Ws[(size_t)(k0 + 2 * d + 1) * M + m]);
  uint4 o;
  o.x = p[0]; o.y = p[1]; o.z = p[2]; o.w = p[3];
  *(uint4*)(os + (size_t)tid * 8) = o;
}

// Pt/Ps = h @ W1 (+b1 on Pt), MFMA, no LDS. 64 nodes/block, 4 waves.
__global__ __launch_bounds__(256) void proj_kernel(
    const ushort_t* __restrict__ hbf, const ushort_t* __restrict__ W1p,
    const float* __restrict__ b1, ushort_t* __restrict__ Ptb, ushort_t* __restrict__ Psb) {
  const int t = threadIdx.x, blk = blockIdx.x;
  const int w = t >> 6, l = t & 63, quad = l >> 4, col = l & 15;
  const ushort_t* hb = hbf + (size_t)blk * 8192;
#pragma unroll
  for (int half = 0; half < 2; ++half) {
    f32x4 acc[4][4];
#pragma unroll
    for (int m = 0; m < 4; ++m)
#pragma unroll
      for (int ct = 0; ct < 4; ++ct) acc[m][ct] = (f32x4){0.f, 0.f, 0.f, 0.f};
#pragma unroll
    for (int ks = 0; ks < 4; ++ks) {
      bf16x8 af[4];
#pragma unroll
      for (int m = 0; m < 4; ++m)
        af[m] = *(const bf16x8*)&W1p[((size_t)((w * 4 + m) * 8 + half * 4 + ks) * 64 + l) * 8];
#pragma unroll
      for (int ct = 0; ct < 4; ++ct) {
        bf16x8 bf = *(const bf16x8*)&hb[((ct * 4 + ks) * 64 + l) * 8];
#pragma unroll
        for (int m = 0; m < 4; ++m)
          acc[m][ct] = __builtin_amdgcn_mfma_f32_16x16x32_bf16(af[m], bf, acc[m][ct], 0, 0, 0);
      }
    }
    ushort_t* out = half ? Psb : Ptb;
#pragma unroll
    for (int m = 0; m < 4; ++m) {
      const int o0 = (w * 4 + m) * 16 + quad * 4;
      f32x4 bb = (f32x4){0.f, 0.f, 0.f, 0.f};
      if (half == 0) bb = *(const f32x4*)(b1 + o0);
#pragma unroll
      for (int ct = 0; ct < 4; ++ct) {
        const size_t node = (size_t)blk * 64 + ct * 16 + col;
        uint2 d;
        d.x = pack2bf(acc[m][ct][0] + bb[0], acc[m][ct][1] + bb[1]);
        d.y = pack2bf(acc[m][ct][2] + bb[2], acc[m][ct][3] + bb[3]);
        *(uint2*)&out[node * HH + o0] = d;
      }
    }
  }
}

// MFMA edge kernel, target-sorted edges, wave-cooperative weights, 4 blocks/CU.
__global__ __launch_bounds__(256, 4) void edge_kernel(
    const int* __restrict__ sSrc, const int* __restrict__ sTgt,
    const ushort_t* __restrict__ Ptb, const ushort_t* __restrict__ Psb,
    const ushort_t* __restrict__ W2p, const float* __restrict__ b2,
    const ushort_t* __restrict__ W3p, const float* __restrict__ b3,
    const float* __restrict__ invc, float* __restrict__ agg) {
  __shared__ __align__(16) float vBf[64 * 132];
  __shared__ int sIdx[64];
  __shared__ int tIdx[64];
  ushort_t* vB = (ushort_t*)vBf;
  const int t = threadIdx.x;
  const int e0 = blockIdx.x * 64;
  if (t < 64) {
    int e = e0 + t;
    int s = 0, tg = -1;
    if (e < ET) { s = sSrc[e]; tg = sTgt[e]; }
    sIdx[t] = s;
    tIdx[t] = tg;
  }
  __syncthreads();
  // stage 1: bf16 gather + tanh -> vB (B-frag order)
  {
    const int el = t & 63, c = t >> 6;
    int tg = tIdx[el]; if (tg < 0) tg = 0;
    const int s = sIdx[el];
    const uint4* pt = (const uint4*)(Ptb + (size_t)tg * HH + c * 64);
    const uint4* ps = (const uint4*)(Psb + (size_t)s * HH + c * 64);
    const int ct = el >> 4, mr = el & 15;
#pragma unroll
    for (int g = 0; g < 8; ++g) {
      uint4 av = pt[g];
      uint4 bv = ps[g];
      uint_t ad[4] = {av.x, av.y, av.z, av.w};
      uint_t bd[4] = {bv.x, bv.y, bv.z, bv.w};
      uint_t p[4];
#pragma unroll
      for (int d = 0; d < 4; ++d) {
        float flo = bflo(ad[d]) + bflo(bd[d]);
        float fhi = bfhi(ad[d]) + bfhi(bd[d]);
        p[d] = pack2bf(fast_tanh(flo), fast_tanh(fhi));
      }
      uint4 o;
      o.x = p[0]; o.y = p[1]; o.z = p[2]; o.w = p[3];
      const int ks = c * 2 + (g >> 2);
      const int quad = g & 3;
      *(uint4*)&vB[((ct * 8 + ks) * 64 + quad * 16 + mr) * 8] = o;
    }
  }
  __syncthreads();
  const int w = t >> 6, l = t & 63;
  const int quad = l >> 4, col = l & 15;
  // stage 2: u^T — wave w does A-rows rt = 4w..4w+3, all 4 edge tiles
  f32x4 acc2[4][4];
#pragma unroll
  for (int rp = 0; rp < 4; ++rp)
#pragma unroll
    for (int ct = 0; ct < 4; ++ct) acc2[rp][ct] = (f32x4){0.f, 0.f, 0.f, 0.f};
#pragma unroll
  for (int ks = 0; ks < 8; ++ks) {
    bf16x8 bfrag[4];
#pragma unroll
    for (int ct = 0; ct < 4; ++ct)
      bfrag[ct] = *(const bf16x8*)&vB[((ct * 8 + ks) * 64 + l) * 8];
#pragma unroll
    for (int rp = 0; rp < 4; ++rp) {
      bf16x8 afrag = *(const bf16x8*)&W2p[((size_t)((w * 4 + rp) * 8 + ks) * 64 + l) * 8];
#pragma unroll
      for (int ct = 0; ct < 4; ++ct)
        acc2[rp][ct] = __builtin_amdgcn_mfma_f32_16x16x32_bf16(afrag, bfrag[ct], acc2[rp][ct], 0, 0, 0);
    }
  }
  __syncthreads();
#pragma unroll
  for (int rp = 0; rp < 4; ++rp) {
    f32x4 bb = *(const f32x4*)(b2 + w * 64 + rp * 16 + quad * 4);
#pragma unroll
    for (int ct = 0; ct < 4; ++ct) {
      uint2 d;
      d.x = pack2bf(fast_tanh(acc2[rp][ct][0] + bb[0]), fast_tanh(acc2[rp][ct][1] + bb[1]));
      d.y = pack2bf(fast_tanh(acc2[rp][ct][2] + bb[2]), fast_tanh(acc2[rp][ct][3] + bb[3]));
      const int gidx = (ct * 8 + w * 2 + (rp >> 1)) * 64 + ((rp & 1) * 2 + (quad >> 1)) * 16 + col;
      *(uint2*)&vB[gidx * 8 + (quad & 1) * 4] = d;
    }
  }
  __syncthreads();
  // stage 3: msg^T — wave w does A-rows 2w..2w+1
  f32x4 acc3[2][4];
#pragma unroll
  for (int rp = 0; rp < 2; ++rp)
#pragma unroll
    for (int ct = 0; ct < 4; ++ct) acc3[rp][ct] = (f32x4){0.f, 0.f, 0.f, 0.f};
#pragma unroll
  for (int ks = 0; ks < 8; ++ks) {
    bf16x8 bfrag[4];
#pragma unroll
    for (int ct = 0; ct < 4; ++ct)
      bfrag[ct] = *(const bf16x8*)&vB[((ct * 8 + ks) * 64 + l) * 8];
#pragma unroll
    for (int rp = 0; rp < 2; ++rp) {
      bf16x8 afrag = *(const bf16x8*)&W3p[((size_t)((w * 2 + rp) * 8 + ks) * 64 + l) * 8];
#pragma unroll
      for (int ct = 0; ct < 4; ++ct)
        acc3[rp][ct] = __builtin_amdgcn_mfma_f32_16x16x32_bf16(afrag, bfrag[ct], acc3[rp][ct], 0, 0, 0);
    }
  }
  __syncthreads();
  {
#pragma unroll
    for (int rp = 0; rp < 2; ++rp) {
      const int m0 = w * 32 + rp * 16 + quad * 4;
      f32x4 b3v = *(const f32x4*)(b3 + m0);
#pragma unroll
      for (int ct = 0; ct < 4; ++ct) {
        float4 o4;
        o4.x = acc3[rp][ct][0] + b3v[0];
        o4.y = acc3[rp][ct][1] + b3v[1];
        o4.z = acc3[rp][ct][2] + b3v[2];
        o4.w = acc3[rp][ct][3] + b3v[3];
        *(float4*)(vBf + (ct * 16 + col) * 132 + m0) = o4;
      }
    }
  }
  __syncthreads();
  // segmented reduction with folded 1/deg
  {
    const int j = t & 127;
    const int hb = t >> 7;
    const float* colp = vBf + j;
    int cur = tIdx[hb * 32];
    float a = 0.f;
    for (int e = hb * 32; e < hb * 32 + 32; ++e) {
      int tg = tIdx[e];
      if (tg != cur) {
        if (cur >= 0) atomicAdd(&agg[(size_t)cur * DD + j], a * invc[cur]);
        a = 0.f;
        cur = tg;
      }
      a += colp[e * 132];
    }
    if (cur >= 0) atomicAdd(&agg[(size_t)cur * DD + j], a * invc[cur]);
  }
}

// Fused GRU (unchanged structure; pk-cvt in packing paths)
__global__ __launch_bounds__(256, 2) void gru_kernel(
    const float* __restrict__ agg, const float* __restrict__ hg,
    const ushort_t* __restrict__ hbf_in,
    const ushort_t* __restrict__ Wihp, const ushort_t* __restrict__ Whhp,
    const float* __restrict__ bih, const float* __restrict__ bhh,
    float* __restrict__ hg_out, ushort_t* __restrict__ hbf_out) {
  __shared__ __align__(16) ushort_t aggF[64 * 128];  // 16 KB, B-frag
  __shared__ __align__(16) float hT[64 * 132];       // 33.8 KB
  const int t = threadIdx.x, blk = blockIdx.x;
  const size_t nodeBase = (size_t)blk * 64;
  {
    const int row = t >> 2, c = t & 3;
    const float4* ap = (const float4*)(agg + (nodeBase + row) * DD + c * 32);
    const int ct = row >> 4, mr = row & 15;
#pragma unroll
    for (int g = 0; g < 8; ++g) {
      float4 v = ap[g];
      uint2 d;
      d.x = pack2bf(v.x, v.y);
      d.y = pack2bf(v.z, v.w);
      *(uint2*)&aggF[(((ct * 4 + c) * 64) + (g >> 1) * 16 + mr) * 8 + (g & 1) * 4] = d;
    }
    const float4* hp = (const float4*)(hg + (nodeBase + row) * DD + c * 32);
    float* hrow = hT + row * 132 + c * 32;
#pragma unroll
    for (int g = 0; g < 8; ++g) *(float4*)(hrow + g * 4) = hp[g];
  }
  __syncthreads();
  const int w = t >> 6, l = t & 63, quad = l >> 4, col = l & 15;
  const ushort_t* hbf_blk = hbf_in + nodeBase * DD;
  f32x4 bbr[2], bbz[2], bbin[2], bbhn[2];
#pragma unroll
  for (int m = 0; m < 2; ++m) {
    const int o = (w + 4 * m) * 16 + quad * 4;
    f32x4 i0 = *(const f32x4*)(bih + o),       h0 = *(const f32x4*)(bhh + o);
    f32x4 i1 = *(const f32x4*)(bih + o + 128), h1 = *(const f32x4*)(bhh + o + 128);
    bbr[m] = i0 + h0;
    bbz[m] = i1 + h1;
    bbin[m] = *(const f32x4*)(bih + o + 256);
    bbhn[m] = *(const f32x4*)(bhh + o + 256);
  }
  for (int ct = 0; ct < 4; ++ct) {
    f32x4 acc[8];
#pragma unroll
    for (int i = 0; i < 8; ++i) acc[i] = (f32x4){0.f, 0.f, 0.f, 0.f};
#pragma unroll
    for (int ks = 0; ks < 8; ++ks) {
      bf16x8 bfrag;
      if (ks < 4) bfrag = *(const bf16x8*)&aggF[((ct * 4 + ks) * 64 + l) * 8];
      else        bfrag = *(const bf16x8*)&hbf_blk[((ct * 4 + (ks - 4)) * 64 + l) * 8];
#pragma unroll
      for (int i = 0; i < 6; ++i) {
        const int rt = w + 4 * i;
        bf16x8 afrag = (ks < 4)
            ? *(const bf16x8*)&Wihp[((size_t)(rt * 4 + ks) * 64 + l) * 8]
            : *(const bf16x8*)&Whhp[((size_t)(rt * 4 + ks - 4) * 64 + l) * 8];
        const int tgt = (i < 4) ? i : ((ks < 4) ? i : i + 2);
        acc[tgt] = __builtin_amdgcn_mfma_f32_16x16x32_bf16(afrag, bfrag, acc[tgt], 0, 0, 0);
      }
    }
#pragma unroll
    for (int m = 0; m < 2; ++m) {
      const int or0 = (w + 4 * m) * 16 + quad * 4;
      float* hrow = hT + (ct * 16 + col) * 132 + or0;
      f32x4 hv = *(const f32x4*)hrow;
      f32x4 hnew;
#pragma unroll
      for (int r = 0; r < 4; ++r) {
        float rr = fast_sigmoid(acc[m][r] + bbr[m][r]);
        float zz = fast_sigmoid(acc[2 + m][r] + bbz[m][r]);
        float gin = acc[4 + m][r] + bbin[m][r];
        float ghn = acc[6 + m][r] + bbhn[m][r];
        float nn = fast_tanh(fmaf(rr, ghn, gin));
        hnew[r] = fmaf(zz, hv[r] - nn, nn);
      }
      *(f32x4*)hrow = hnew;
      uint2 d;
      d.x = pack2bf(hnew[0], hnew[1]);
      d.y = pack2bf(hnew[2], hnew[3]);
      const int ksn = 2 * m + (w >> 1);
      const int qn = 2 * (w & 1) + (quad >> 1);
      *(uint2*)&hbf_out[nodeBase * DD + (((ct * 4 + ksn) * 64) + qn * 16 + col) * 8 + 4 * (quad & 1)] = d;
    }
  }
  __syncthreads();
  {
    const int row = t >> 2, c = t & 3;
    float* dst = hg_out + (nodeBase + row) * DD + c * 32;
    const float* src = hT + row * 132 + c * 32;
#pragma unroll
    for (int g = 0; g < 8; ++g) *(float4*)(dst + g * 4) = *(const float4*)(src + g * 4);
  }
}

// Fused decoder (unchanged structure; pk-cvt in o1 pack)
__global__ __launch_bounds__(256) void dec_kernel(
    const ushort_t* __restrict__ hbf, const ushort_t* __restrict__ W1p,
    const float* __restrict__ b1, const ushort_t* __restrict__ W2p,
    const float* __restrict__ b2, const float* __restrict__ w3,
    const float* __restrict__ b3, float* __restrict__ out) {
  __shared__ __align__(16) ushort_t o1F[64 * 256];  // 32 KB
  __shared__ float red[16][64];                     // 4 KB
  const int t = threadIdx.x, blk = blockIdx.x;
  const int w = t >> 6, l = t & 63, quad = l >> 4, col = l & 15;
  const ushort_t* hb = hbf + (size_t)blk * 8192;
  {
    f32x4 a1[4][4];
#pragma unroll
    for (int m = 0; m < 4; ++m)
#pragma unroll
      for (int ct = 0; ct < 4; ++ct) a1[m][ct] = (f32x4){0.f, 0.f, 0.f, 0.f};
#pragma unroll
    for (int ks = 0; ks < 4; ++ks) {
      bf16x8 af[4];
#pragma unroll
      for (int m = 0; m < 4; ++m)
        af[m] = *(const bf16x8*)&W1p[((size_t)((w * 4 + m) * 4 + ks) * 64 + l) * 8];
#pragma unroll
      for (int ct = 0; ct < 4; ++ct) {
        bf16x8 bf = *(const bf16x8*)&hb[((ct * 4 + ks) * 64 + l) * 8];
#pragma unroll
        for (int m = 0; m < 4; ++m)
          a1[m][ct] = __builtin_amdgcn_mfma_f32_16x16x32_bf16(af[m], bf, a1[m][ct], 0, 0, 0);
      }
    }
#pragma unroll
    for (int m = 0; m < 4; ++m) {
      const int o0 = (w * 4 + m) * 16 + quad * 4;
      f32x4 bb = *(const f32x4*)(b1 + o0);
      const int ks1 = 2 * w + (m >> 1);
      const int q1 = 2 * (m & 1) + (quad >> 1);
#pragma unroll
      for (int ct = 0; ct < 4; ++ct) {
        uint2 d;
        d.x = pack2bf(fast_tanh(a1[m][ct][0] + bb[0]), fast_tanh(a1[m][ct][1] + bb[1]));
        d.y = pack2bf(fast_tanh(a1[m][ct][2] + bb[2]), fast_tanh(a1[m][ct][3] + bb[3]));
        *(uint2*)&o1F[((ct * 8 + ks1) * 64 + q1 * 16 + col) * 8 + 4 * (quad & 1)] = d;
      }
    }
  }
  __syncthreads();
  {
    f32x4 a2[4][4];
#pragma unroll
    for (int m = 0; m < 4; ++m)
#pragma unroll
      for (int ct = 0; ct < 4; ++ct) a2[m][ct] = (f32x4){0.f, 0.f, 0.f, 0.f};
#pragma unroll
    for (int ks = 0; ks < 8; ++ks) {
      bf16x8 af[4];
#pragma unroll
      for (int m = 0; m < 4; ++m)
        af[m] = *(const bf16x8*)&W2p[((size_t)((w * 4 + m) * 8 + ks) * 64 + l) * 8];
#pragma unroll
      for (int ct = 0; ct < 4; ++ct) {
        bf16x8 bf = *(const bf16x8*)&o1F[((ct * 8 + ks) * 64 + l) * 8];
#pragma unroll
        for (int m = 0; m < 4; ++m)
          a2[m][ct] = __builtin_amdgcn_mfma_f32_16x16x32_bf16(af[m], bf, a2[m][ct], 0, 0, 0);
      }
    }
    float partial[4] = {0.f, 0.f, 0.f, 0.f};
#pragma unroll
    for (int m = 0; m < 4; ++m) {
      const int o0 = (w * 4 + m) * 16 + quad * 4;
      f32x4 b2v = *(const f32x4*)(b2 + o0);
      f32x4 w3v = *(const f32x4*)(w3 + o0);
#pragma unroll
      for (int ct = 0; ct < 4; ++ct)
#pragma unroll
        for (int r = 0; r < 4; ++r)
          partial[ct] += fast_tanh(a2[m][ct][r] + b2v[r]) * w3v[r];
    }
#pragma unroll
    for (int ct = 0; ct < 4; ++ct) red[w * 4 + quad][ct * 16 + col] = partial[ct];
  }
  __syncthreads();
  if (t < 64) {
    float s = b3[0];
#pragma unroll
    for (int k = 0; k < 16; ++k) s += red[k][t];
    size_t node = (size_t)blk * 64 + t;
    if (node < NN) out[node] = s;
  }
}

extern "C" void kernel_launch(void* const* d_in, const int* in_sizes, int n_in,
                              void* d_out, int out_size, void* d_ws, size_t ws_size,
                              hipStream_t stream) {
  const float* x      = (const float*)d_in[0];
  const int*   ei     = (const int*)d_in[1];
  const float* enc_W  = (const float*)d_in[2];
  const float* enc_b  = (const float*)d_in[3];
  const float* msg_W1 = (const float*)d_in[4];
  const float* msg_b1 = (const float*)d_in[5];
  const float* msg_W2 = (const float*)d_in[6];
  const float* msg_b2 = (const float*)d_in[7];
  const float* msg_W3 = (const float*)d_in[8];
  const float* msg_b3 = (const float*)d_in[9];
  const float* gWih   = (const float*)d_in[10];
  const float* gWhh   = (const float*)d_in[11];
  const float* gbih   = (const float*)d_in[12];
  const float* gbhh   = (const float*)d_in[13];
  const float* dW1    = (const float*)d_in[14];
  const float* db1    = (const float*)d_in[15];
  const float* dW2    = (const float*)d_in[16];
  const float* db2    = (const float*)d_in[17];
  const float* dW3    = (const float*)d_in[18];
  const float* db3    = (const float*)d_in[19];
  float* out = (float*)d_out;

  float* ws = (float*)d_ws;
  float* invc = ws;                                    // NP
  float* h    = ws + NP;                               // NP*128 fp32
  float* agg  = h + (size_t)NP * DD;                   // NP*128 fp32
  ushort_t* hbfA = (ushort_t*)(agg + (size_t)NP * DD); // NP*128 ush
  ushort_t* hbfB = hbfA + (size_t)NP * DD;             // NP*128 ush
  ushort_t* Ptb  = hbfB + (size_t)NP * DD;             // NP*256 ush
  ushort_t* Psb  = Ptb + (size_t)NP * HH;              // NP*256 ush
  ushort_t* W2pk = Psb + (size_t)NP * HH;              // 3*65536
  ushort_t* W3pk = W2pk + 3 * 65536;                   // 3*32768
  ushort_t* W1pk = W3pk + 3 * 32768;                   // 3*65536
  ushort_t* Wihpk = W1pk + 3 * 65536;                  // 3*49152
  ushort_t* Whhpk = Wihpk + 3 * 49152;                 // 3*49152
  ushort_t* dW1pk = Whhpk + 3 * 49152;                 // 32768
  ushort_t* dW2pk = dW1pk + 32768;                     // 65536
  int* deg    = (int*)(dW2pk + 65536);                 // NP
  int* cursor = deg + NP;                              // NP
  int* sSrc   = cursor + NP;                           // ET
  int* sTgt   = sSrc + ET;                             // ET

  const int* esrc = ei;
  const int* etgt = ei + NE;

  // edge sort (once)
  hipMemsetAsync(deg, 0, NN * sizeof(int), stream);
  deg_kernel<<<(ET + 255) / 256, 256, 0, stream>>>(etgt, deg);
  scan_kernel<<<1, 1024, 0, stream>>>(deg, cursor, invc);
  scatter_kernel<<<(ET + 255) / 256, 256, 0, stream>>>(esrc, etgt, cursor, sSrc, sTgt);

  encoder_kernel<<<(NN * DD + 255) / 256, 256, 0, stream>>>(x, enc_W, enc_b, h, hbfA);

  // weight packs (once, all layers)
  pack_kernel<<<dim3(32, 3), 256, 0, stream>>>(msg_W2, W2pk, 256, 3, 128, 65536, 65536);
  pack_kernel<<<dim3(16, 3), 256, 0, stream>>>(msg_W3, W3pk, 128, 3, 64, 32768, 32768);
  pack_kernel<<<dim3(32, 3), 256, 0, stream>>>(msg_W1, W1pk, 256, 3, 128, 65536, 65536);
  pack_kernel<<<dim3(24, 3), 256, 0, stream>>>(gWih, Wihpk, 384, 2, 96, 49152, 49152);
  pack_kernel<<<dim3(24, 3), 256, 0, stream>>>(gWhh, Whhpk, 384, 2, 96, 49152, 49152);
  pack_kernel<<<dim3(16, 1), 256, 0, stream>>>(dW1, dW1pk, 256, 2, 64, 0, 0);
  pack_kernel<<<dim3(32, 1), 256, 0, stream>>>(dW2, dW2pk, 256, 3, 128, 0, 0);

  for (int l = 0; l < NLAYERS; ++l) {
    const ushort_t* hin = (l & 1) ? hbfB : hbfA;
    ushort_t* hout = (l & 1) ? hbfA : hbfB;
    proj_kernel<<<NB, 256, 0, stream>>>(hin, W1pk + (size_t)l * 65536, msg_b1 + l * HH, Ptb, Psb);
    hipMemsetAsync(agg, 0, (size_t)NP * DD * sizeof(float), stream);
    edge_kernel<<<(ET + 63) / 64, 256, 0, stream>>>(
        sSrc, sTgt, Ptb, Psb, W2pk + (size_t)l * 65536, msg_b2 + (size_t)l * HH,
        W3pk + (size_t)l * 32768, msg_b3 + (size_t)l * DD, invc, agg);
    gru_kernel<<<NB, 256, 0, stream>>>(
        agg, h, hin, Wihpk + (size_t)l * 49152, Whhpk + (size_t)l * 49152,
        gbih + (size_t)l * 3 * DD, gbhh + (size_t)l * 3 * DD, h, hout);
  }
  dec_kernel<<<NB, 256, 0, stream>>>(hbfB, dW1pk, db1, dW2pk, db2, dW3, db3, out);
}